// Round 1
// baseline (4323.652 us; speedup 1.0000x reference)
//
#include <hip/hip_runtime.h>

#define N_NODES  200000
#define N_EDGES  600000
#define N_GRAPHS 4000
#define IN_DIM   25
#define EDGE_DIM 11
#define HIDDEN   128
#define DEPTH    4
#define BN_EPS   1e-5f

#define EB 32   // edges per block in edge kernel
#define NB 16   // nodes per block in update kernel

__device__ __forceinline__ float lrelu(float v) { return v > 0.f ? v : 0.1f * v; }

// ---------------- input projection: h = lrelu(x @ W_in + b_in) ----------------
__global__ __launch_bounds__(128) void k_input_proj(const float* __restrict__ x,
                                                    const float* __restrict__ W,
                                                    const float* __restrict__ b,
                                                    float* __restrict__ h)
{
    const int t  = threadIdx.x;
    const int n0 = blockIdx.x * 8;
    __shared__ float sW[IN_DIM * HIDDEN];
    __shared__ float sx[8][IN_DIM];
    for (int i = t; i < IN_DIM * HIDDEN; i += 128) sW[i] = W[i];
    for (int i = t; i < 8 * IN_DIM; i += 128) {
        int n = i / IN_DIM, k = i % IN_DIM;
        sx[n][k] = x[(size_t)(n0 + n) * IN_DIM + k];
    }
    __syncthreads();
    const float bt = b[t];
    for (int n = 0; n < 8; ++n) {
        float acc = bt;
        #pragma unroll
        for (int k = 0; k < IN_DIM; ++k) acc += sx[n][k] * sW[k * HIDDEN + t];
        h[(size_t)(n0 + n) * HIDDEN + t] = lrelu(acc);
    }
}

// ------- fused edge message GEMM + lrelu + scatter-add (atomic) -------
// msg = lrelu(cat[h[src], edge_attr] @ W_msg + b_msg); aggr[dst] += msg
__global__ __launch_bounds__(128) void k_edge_msg(const float* __restrict__ h,
                                                  const int*   __restrict__ ei,
                                                  const float* __restrict__ ea,
                                                  const float* __restrict__ W,
                                                  const float* __restrict__ b,
                                                  float* __restrict__ aggr)
{
    const int t  = threadIdx.x;
    const int e0 = blockIdx.x * EB;
    __shared__ __align__(16) float s_in[EB][HIDDEN + EDGE_DIM + 1]; // 140 floats/row, 560B (16B mult)
    __shared__ int s_dst[EB];

    if (t < EB) s_dst[t] = ei[N_EDGES + e0 + t];
    for (int e = 0; e < EB; ++e) {
        const int src = ei[e0 + e];                 // uniform per block iteration
        s_in[e][t] = h[(size_t)src * HIDDEN + t];
    }
    for (int i = t; i < EB * EDGE_DIM; i += 128) {
        int e = i / EDGE_DIM, j = i % EDGE_DIM;
        s_in[e][HIDDEN + j] = ea[(size_t)(e0 + e) * EDGE_DIM + j];
    }
    __syncthreads();

    const int K = HIDDEN + EDGE_DIM; // 139
    float acc[EB];
    const float bt = b[t];
    #pragma unroll
    for (int e = 0; e < EB; ++e) acc[e] = bt;

    int k = 0;
    for (; k + 4 <= K; k += 4) {
        const float w0 = W[(k + 0) * HIDDEN + t];
        const float w1 = W[(k + 1) * HIDDEN + t];
        const float w2 = W[(k + 2) * HIDDEN + t];
        const float w3 = W[(k + 3) * HIDDEN + t];
        #pragma unroll
        for (int e = 0; e < EB; ++e) {
            const float4 v = *reinterpret_cast<const float4*>(&s_in[e][k]);
            acc[e] += v.x * w0 + v.y * w1 + v.z * w2 + v.w * w3;
        }
    }
    for (; k < K; ++k) {
        const float w = W[k * HIDDEN + t];
        #pragma unroll
        for (int e = 0; e < EB; ++e) acc[e] += s_in[e][k] * w;
    }

    #pragma unroll
    for (int e = 0; e < EB; ++e) {
        atomicAdd(&aggr[(size_t)s_dst[e] * HIDDEN + t], lrelu(acc[e]));
    }
}

// ------- update GEMM: out = relu(cat[aggr, h] @ W_up + b_up), in-place over aggr -------
// (relu(lrelu(x)) == relu(x))
__global__ __launch_bounds__(128) void k_update(float* __restrict__ aggr,
                                                const float* __restrict__ h,
                                                const float* __restrict__ W,
                                                const float* __restrict__ b)
{
    const int t  = threadIdx.x;
    const int n0 = blockIdx.x * NB;
    __shared__ __align__(16) float s_in[NB][2 * HIDDEN];
    for (int n = 0; n < NB; ++n) {
        s_in[n][t]          = aggr[(size_t)(n0 + n) * HIDDEN + t];
        s_in[n][HIDDEN + t] = h[(size_t)(n0 + n) * HIDDEN + t];
    }
    __syncthreads();

    float acc[NB];
    const float bt = b[t];
    #pragma unroll
    for (int n = 0; n < NB; ++n) acc[n] = bt;

    for (int k = 0; k < 2 * HIDDEN; k += 4) {
        const float w0 = W[(k + 0) * HIDDEN + t];
        const float w1 = W[(k + 1) * HIDDEN + t];
        const float w2 = W[(k + 2) * HIDDEN + t];
        const float w3 = W[(k + 3) * HIDDEN + t];
        #pragma unroll
        for (int n = 0; n < NB; ++n) {
            const float4 v = *reinterpret_cast<const float4*>(&s_in[n][k]);
            acc[n] += v.x * w0 + v.y * w1 + v.z * w2 + v.w * w3;
        }
    }
    #pragma unroll
    for (int n = 0; n < NB; ++n) {
        aggr[(size_t)(n0 + n) * HIDDEN + t] = fmaxf(acc[n], 0.f);
    }
}

// ------- BN batch stats: per-feature sum and sumsq -------
__global__ __launch_bounds__(128) void k_bn_stats(const float* __restrict__ out,
                                                  float* __restrict__ sum,
                                                  float* __restrict__ sumsq)
{
    const int t = threadIdx.x;
    float s = 0.f, q = 0.f;
    for (int n = blockIdx.x; n < N_NODES; n += gridDim.x) {
        const float v = out[(size_t)n * HIDDEN + t];
        s += v; q += v * v;
    }
    atomicAdd(&sum[t], s);
    atomicAdd(&sumsq[t], q);
}

__global__ void k_bn_finalize(const float* __restrict__ sum,
                              const float* __restrict__ sumsq,
                              const float* __restrict__ gamma,
                              const float* __restrict__ beta,
                              float* __restrict__ scale,
                              float* __restrict__ shift)
{
    const int t = threadIdx.x;
    const float mu  = sum[t]   * (1.f / N_NODES);
    const float var = sumsq[t] * (1.f / N_NODES) - mu * mu;
    const float sc  = gamma[t] * rsqrtf(var + BN_EPS);
    scale[t] = sc;
    shift[t] = beta[t] - mu * sc;
}

__global__ __launch_bounds__(256) void k_bn_norm(const float* __restrict__ out,
                                                 const float* __restrict__ scale,
                                                 const float* __restrict__ shift,
                                                 float* __restrict__ h)
{
    const size_t total = (size_t)N_NODES * HIDDEN;
    for (size_t i = (size_t)blockIdx.x * 256 + threadIdx.x; i < total; i += (size_t)gridDim.x * 256) {
        const int t = (int)(i & (HIDDEN - 1));
        h[i] = out[i] * scale[t] + shift[t];
    }
}

// ------- mean pool over graphs -------
__global__ void k_pool_cnt(const int* __restrict__ batch, float* __restrict__ cnt)
{
    const int n = blockIdx.x * 256 + threadIdx.x;
    if (n < N_NODES) atomicAdd(&cnt[batch[n]], 1.0f);
}

__global__ __launch_bounds__(128) void k_pool_sum(const float* __restrict__ h,
                                                  const int* __restrict__ batch,
                                                  float* __restrict__ pool)
{
    const int t  = threadIdx.x;
    const int n0 = blockIdx.x * 16;
    __shared__ int sb[16];
    if (t < 16) sb[t] = batch[n0 + t];
    __syncthreads();
    int g = sb[0];
    float acc = 0.f;
    for (int j = 0; j < 16; ++j) {
        const float v = h[(size_t)(n0 + j) * HIDDEN + t];
        if (sb[j] != g) {
            atomicAdd(&pool[(size_t)g * HIDDEN + t], acc);
            g = sb[j];
            acc = v;
        } else {
            acc += v;
        }
    }
    atomicAdd(&pool[(size_t)g * HIDDEN + t], acc);
}

__global__ void k_pool_div(const float* __restrict__ pool,
                           const float* __restrict__ cnt,
                           float* __restrict__ out)
{
    const int i = blockIdx.x * 256 + threadIdx.x;
    if (i < N_GRAPHS * HIDDEN) {
        const int g = i >> 7;
        out[i] = pool[i] / fmaxf(cnt[g], 1.0f);
    }
}

extern "C" void kernel_launch(void* const* d_in, const int* in_sizes, int n_in,
                              void* d_out, int out_size, void* d_ws, size_t ws_size,
                              hipStream_t stream)
{
    const float* x     = (const float*)d_in[0];
    const int*   ei    = (const int*)  d_in[1];
    const float* ea    = (const float*)d_in[2];
    const int*   batch = (const int*)  d_in[3];
    const float* W_in  = (const float*)d_in[4];
    const float* b_in  = (const float*)d_in[5];
    const float* W_msg = (const float*)d_in[6];
    const float* b_msg = (const float*)d_in[7];
    const float* W_up  = (const float*)d_in[8];
    const float* b_up  = (const float*)d_in[9];
    const float* gamma = (const float*)d_in[10];
    const float* beta  = (const float*)d_in[11];
    float* out = (float*)d_out;

    float* h        = (float*)d_ws;                         // N*128
    float* buf      = h + (size_t)N_NODES * HIDDEN;         // N*128 (aggr / pre-BN out)
    float* bn_sum   = buf + (size_t)N_NODES * HIDDEN;       // 128
    float* bn_sumsq = bn_sum + HIDDEN;                      // 128
    float* bn_scale = bn_sumsq + HIDDEN;                    // 128
    float* bn_shift = bn_scale + HIDDEN;                    // 128
    float* pool     = bn_shift + HIDDEN;                    // G*128
    float* cnt      = pool + (size_t)N_GRAPHS * HIDDEN;     // G

    k_input_proj<<<N_NODES / 8, 128, 0, stream>>>(x, W_in, b_in, h);

    for (int d = 0; d < DEPTH; ++d) {
        hipMemsetAsync(buf, 0, (size_t)N_NODES * HIDDEN * sizeof(float), stream);
        hipMemsetAsync(bn_sum, 0, 2 * HIDDEN * sizeof(float), stream);
        k_edge_msg<<<N_EDGES / EB, 128, 0, stream>>>(
            h, ei, ea,
            W_msg + (size_t)d * (HIDDEN + EDGE_DIM) * HIDDEN,
            b_msg + (size_t)d * HIDDEN, buf);
        k_update<<<N_NODES / NB, 128, 0, stream>>>(
            buf, h,
            W_up + (size_t)d * 2 * HIDDEN * HIDDEN,
            b_up + (size_t)d * HIDDEN);
        k_bn_stats<<<256, 128, 0, stream>>>(buf, bn_sum, bn_sumsq);
        k_bn_finalize<<<1, 128, 0, stream>>>(bn_sum, bn_sumsq,
                                             gamma + (size_t)d * HIDDEN,
                                             beta + (size_t)d * HIDDEN,
                                             bn_scale, bn_shift);
        k_bn_norm<<<2048, 256, 0, stream>>>(buf, bn_scale, bn_shift, h);
    }

    hipMemsetAsync(pool, 0, ((size_t)N_GRAPHS * HIDDEN + N_GRAPHS) * sizeof(float), stream);
    k_pool_cnt<<<(N_NODES + 255) / 256, 256, 0, stream>>>(batch, cnt);
    k_pool_sum<<<N_NODES / 16, 128, 0, stream>>>(h, batch, pool);
    k_pool_div<<<(N_GRAPHS * HIDDEN + 255) / 256, 256, 0, stream>>>(pool, cnt, out);
}

// Round 2
// 2797.657 us; speedup vs baseline: 1.5455x; 1.5455x over previous
//
#include <hip/hip_runtime.h>

#define N_NODES  200000
#define N_EDGES  600000
#define N_GRAPHS 4000
#define IN_DIM   25
#define EDGE_DIM 11
#define HIDDEN   128
#define DEPTH    4
#define BN_EPS   1e-5f

typedef unsigned short ushortT;
typedef __attribute__((ext_vector_type(8))) short short8v;
typedef __attribute__((ext_vector_type(4))) float float4v;

__device__ __forceinline__ float lrelu(float v) { return v > 0.f ? v : 0.1f * v; }

__device__ __forceinline__ ushortT f2bf(float f) {
    unsigned u = __builtin_bit_cast(unsigned, f);
    u = (u + 0x7fffu + ((u >> 16) & 1u)) >> 16;
    return (ushortT)u;
}
__device__ __forceinline__ float bf2f(ushortT h) {
    unsigned u = ((unsigned)h) << 16;
    return __builtin_bit_cast(float, u);
}

// ---------------- prep: edge_attr -> padded bf16 [N_EDGES][32] (cols 11..31 = 0) ----------------
__global__ __launch_bounds__(256) void k_prep_ea(const float* __restrict__ ea,
                                                 ushortT* __restrict__ ea16)
{
    const size_t i = (size_t)blockIdx.x * 256 + threadIdx.x;
    if (i >= (size_t)N_EDGES * 32) return;
    const int e = (int)(i >> 5), c = (int)(i & 31);
    ea16[i] = (c < EDGE_DIM) ? f2bf(ea[(size_t)e * EDGE_DIM + c]) : (ushortT)0;
}

// ---------------- prep: W_msg -> B-fragment layout, K padded 139->160 ----------------
// frag index: [d][((kt*8+ct)*64+lane)*8+j], k = kt*32 + (lane>>4)*8 + j, c = ct*16 + (lane&15)
__global__ __launch_bounds__(256) void k_prep_wmsg(const float* __restrict__ W,
                                                   ushortT* __restrict__ Wf)
{
    const int i = blockIdx.x * 256 + threadIdx.x;
    if (i >= DEPTH * 20480) return;
    const int d = i / 20480, r = i % 20480;
    const int j = r & 7, lane = (r >> 3) & 63, tile = r >> 9;
    const int ct = tile & 7, kt = tile >> 3;
    const int k = kt * 32 + ((lane >> 4) << 3) + j;
    const int c = ct * 16 + (lane & 15);
    Wf[i] = (k < HIDDEN + EDGE_DIM)
          ? f2bf(W[((size_t)d * (HIDDEN + EDGE_DIM) + k) * HIDDEN + c]) : (ushortT)0;
}

// ---------------- prep: W_up -> B-fragment layout, K = 256 ----------------
__global__ __launch_bounds__(256) void k_prep_wup(const float* __restrict__ W,
                                                  ushortT* __restrict__ Wf)
{
    const int i = blockIdx.x * 256 + threadIdx.x;
    if (i >= DEPTH * 32768) return;
    const int d = i / 32768, r = i % 32768;
    const int j = r & 7, lane = (r >> 3) & 63, tile = r >> 9;
    const int ct = tile & 7, kt = tile >> 3;
    const int k = kt * 32 + ((lane >> 4) << 3) + j;
    const int c = ct * 16 + (lane & 15);
    Wf[i] = f2bf(W[((size_t)d * 2 * HIDDEN + k) * HIDDEN + c]);
}

// ---------------- input projection: h16 = bf16(lrelu(x @ W_in + b_in)) ----------------
__global__ __launch_bounds__(128) void k_input_proj(const float* __restrict__ x,
                                                    const float* __restrict__ W,
                                                    const float* __restrict__ b,
                                                    ushortT* __restrict__ h16)
{
    const int t  = threadIdx.x;
    const int n0 = blockIdx.x * 8;
    __shared__ float sW[IN_DIM * HIDDEN];
    __shared__ float sx[8][IN_DIM];
    for (int i = t; i < IN_DIM * HIDDEN; i += 128) sW[i] = W[i];
    for (int i = t; i < 8 * IN_DIM; i += 128) {
        int n = i / IN_DIM, k = i % IN_DIM;
        sx[n][k] = x[(size_t)(n0 + n) * IN_DIM + k];
    }
    __syncthreads();
    const float bt = b[t];
    for (int n = 0; n < 8; ++n) {
        float acc = bt;
        #pragma unroll
        for (int k = 0; k < IN_DIM; ++k) acc += sx[n][k] * sW[k * HIDDEN + t];
        h16[(size_t)(n0 + n) * HIDDEN + t] = f2bf(lrelu(acc));
    }
}

// ------- fused edge message MFMA GEMM + lrelu + scatter-add -------
// A = cat[h16[src], ea16] (64 edges x 160), B = W_msg frag (160x128), atomicAdd at dst
__global__ __launch_bounds__(256) void k_edge_mfma(const ushortT* __restrict__ h16,
                                                   const int*     __restrict__ ei,
                                                   const ushortT* __restrict__ ea16,
                                                   const ushortT* __restrict__ Wf,
                                                   const float*   __restrict__ bmsg,
                                                   float*         __restrict__ aggr)
{
    const int t    = threadIdx.x;
    const int wave = t >> 6, lane = t & 63;
    const int e0   = blockIdx.x * 64;

    __shared__ __align__(16) ushortT sA[64][168];   // stride 168: 2-way banks (free)
    __shared__ int sSrc[64];
    __shared__ int sDst[64];

    if (t < 64) { sSrc[t] = ei[e0 + t]; sDst[t] = ei[N_EDGES + e0 + t]; }
    __syncthreads();

    // stage h16 rows: 64 edges x 16 uint4 (256B each)
    for (int i = t; i < 64 * 16; i += 256) {
        const int e = i >> 4, q = i & 15;
        const uint4 v = reinterpret_cast<const uint4*>(h16)[(size_t)sSrc[e] * 16 + q];
        *reinterpret_cast<uint4*>(&sA[e][q * 8]) = v;
    }
    // stage padded edge_attr: 64 edges x 4 uint4 (cols 128..159)
    for (int i = t; i < 64 * 4; i += 256) {
        const int e = i >> 2, q = i & 3;
        const uint4 v = reinterpret_cast<const uint4*>(ea16)[((size_t)(e0 + e)) * 4 + q];
        *reinterpret_cast<uint4*>(&sA[e][128 + q * 8]) = v;
    }
    __syncthreads();

    float4v acc[8];
    #pragma unroll
    for (int ct = 0; ct < 8; ++ct) acc[ct] = (float4v)(0.f);

    const int rowA = wave * 16 + (lane & 15);
    const int kOff = (lane >> 4) * 8;
    for (int kt = 0; kt < 5; ++kt) {
        const short8v a = *reinterpret_cast<const short8v*>(&sA[rowA][kt * 32 + kOff]);
        const short8v* wp = reinterpret_cast<const short8v*>(Wf) + (size_t)(kt * 8) * 64 + lane;
        #pragma unroll
        for (int ct = 0; ct < 8; ++ct) {
            const short8v bfr = wp[ct * 64];
            acc[ct] = __builtin_amdgcn_mfma_f32_16x16x32_bf16(a, bfr, acc[ct], 0, 0, 0);
        }
    }

    // epilogue: bias + lrelu + scatter atomicAdd
    const int col = lane & 15;
    const int r0  = (lane >> 4) * 4;
    #pragma unroll
    for (int ct = 0; ct < 8; ++ct) {
        const float bt = bmsg[ct * 16 + col];
        #pragma unroll
        for (int j = 0; j < 4; ++j) {
            const int e = wave * 16 + r0 + j;
            const float v = lrelu(acc[ct][j] + bt);
            atomicAdd(&aggr[(size_t)sDst[e] * HIDDEN + ct * 16 + col], v);
        }
    }
}

// ------- update MFMA GEMM: relu(cat[aggr, h16] @ W_up + b_up), in-place fp32, fused BN stats -------
__global__ __launch_bounds__(256) void k_update_mfma(float*         __restrict__ aggr,
                                                     const ushortT* __restrict__ h16,
                                                     const ushortT* __restrict__ Wf,
                                                     const float*   __restrict__ bup,
                                                     float*         __restrict__ bn_sum,
                                                     float*         __restrict__ bn_sumsq)
{
    const int t    = threadIdx.x;
    const int wave = t >> 6, lane = t & 63;
    const int n0   = blockIdx.x * 64;

    __shared__ __align__(16) ushortT sA[64][264];   // stride 264: 2-way banks (free)

    // stage aggr fp32 -> bf16 (cols 0..127)
    for (int i = t; i < 64 * 32; i += 256) {
        const int n = i >> 5, q = i & 31;
        const float4 v = reinterpret_cast<const float4*>(aggr)[(size_t)(n0 + n) * 32 + q];
        union { ushortT s[4]; uint2 u; } p;
        p.s[0] = f2bf(v.x); p.s[1] = f2bf(v.y); p.s[2] = f2bf(v.z); p.s[3] = f2bf(v.w);
        *reinterpret_cast<uint2*>(&sA[n][q * 4]) = p.u;
    }
    // stage h16 (cols 128..255)
    for (int i = t; i < 64 * 16; i += 256) {
        const int n = i >> 4, q = i & 15;
        const uint4 v = reinterpret_cast<const uint4*>(h16)[(size_t)(n0 + n) * 16 + q];
        *reinterpret_cast<uint4*>(&sA[n][128 + q * 8]) = v;
    }
    __syncthreads();

    float4v acc[8];
    #pragma unroll
    for (int ct = 0; ct < 8; ++ct) acc[ct] = (float4v)(0.f);

    const int rowA = wave * 16 + (lane & 15);
    const int kOff = (lane >> 4) * 8;
    for (int kt = 0; kt < 8; ++kt) {
        const short8v a = *reinterpret_cast<const short8v*>(&sA[rowA][kt * 32 + kOff]);
        const short8v* wp = reinterpret_cast<const short8v*>(Wf) + (size_t)(kt * 8) * 64 + lane;
        #pragma unroll
        for (int ct = 0; ct < 8; ++ct) {
            const short8v bfr = wp[ct * 64];
            acc[ct] = __builtin_amdgcn_mfma_f32_16x16x32_bf16(a, bfr, acc[ct], 0, 0, 0);
        }
    }

    // epilogue: bias + relu, write fp32 in-place, fused BN partial stats
    const int col = lane & 15;
    const int r0  = (lane >> 4) * 4;
    #pragma unroll
    for (int ct = 0; ct < 8; ++ct) {
        const float bt = bup[ct * 16 + col];
        float s = 0.f, q = 0.f;
        #pragma unroll
        for (int j = 0; j < 4; ++j) {
            const float v = fmaxf(acc[ct][j] + bt, 0.f);
            s += v; q += v * v;
            aggr[(size_t)(n0 + wave * 16 + r0 + j) * HIDDEN + ct * 16 + col] = v;
        }
        s += __shfl_xor(s, 16); s += __shfl_xor(s, 32);
        q += __shfl_xor(q, 16); q += __shfl_xor(q, 32);
        if (lane < 16) {
            atomicAdd(&bn_sum[ct * 16 + col], s);
            atomicAdd(&bn_sumsq[ct * 16 + col], q);
        }
    }
}

__global__ void k_bn_finalize(const float* __restrict__ sum,
                              const float* __restrict__ sumsq,
                              const float* __restrict__ gamma,
                              const float* __restrict__ beta,
                              float* __restrict__ scale,
                              float* __restrict__ shift)
{
    const int t = threadIdx.x;
    const float mu  = sum[t]   * (1.f / N_NODES);
    const float var = sumsq[t] * (1.f / N_NODES) - mu * mu;
    const float sc  = gamma[t] * rsqrtf(var + BN_EPS);
    scale[t] = sc;
    shift[t] = beta[t] - mu * sc;
}

// ------- BN normalize: buf fp32 -> h16 bf16 -------
__global__ __launch_bounds__(256) void k_bn_norm(const float* __restrict__ buf,
                                                 const float* __restrict__ scale,
                                                 const float* __restrict__ shift,
                                                 ushortT* __restrict__ h16)
{
    const size_t i = (size_t)blockIdx.x * 256 + threadIdx.x;   // one float4 per thread
    if (i >= (size_t)N_NODES * HIDDEN / 4) return;
    const float4 v = reinterpret_cast<const float4*>(buf)[i];
    const int c0 = (int)((i * 4) & (HIDDEN - 1));
    union { ushortT s[4]; uint2 u; } p;
    p.s[0] = f2bf(v.x * scale[c0 + 0] + shift[c0 + 0]);
    p.s[1] = f2bf(v.y * scale[c0 + 1] + shift[c0 + 1]);
    p.s[2] = f2bf(v.z * scale[c0 + 2] + shift[c0 + 2]);
    p.s[3] = f2bf(v.w * scale[c0 + 3] + shift[c0 + 3]);
    reinterpret_cast<uint2*>(h16)[i] = p.u;
}

// ------- mean pool over graphs -------
__global__ void k_pool_cnt(const int* __restrict__ batch, float* __restrict__ cnt)
{
    const int n = blockIdx.x * 256 + threadIdx.x;
    if (n < N_NODES) atomicAdd(&cnt[batch[n]], 1.0f);
}

__global__ __launch_bounds__(128) void k_pool_sum(const ushortT* __restrict__ h16,
                                                  const int* __restrict__ batch,
                                                  float* __restrict__ pool)
{
    const int t  = threadIdx.x;
    const int n0 = blockIdx.x * 16;
    __shared__ int sb[16];
    if (t < 16) sb[t] = batch[n0 + t];
    __syncthreads();
    int g = sb[0];
    float acc = 0.f;
    for (int j = 0; j < 16; ++j) {
        const float v = bf2f(h16[(size_t)(n0 + j) * HIDDEN + t]);
        if (sb[j] != g) {
            atomicAdd(&pool[(size_t)g * HIDDEN + t], acc);
            g = sb[j];
            acc = v;
        } else {
            acc += v;
        }
    }
    atomicAdd(&pool[(size_t)g * HIDDEN + t], acc);
}

__global__ void k_pool_div(const float* __restrict__ pool,
                           const float* __restrict__ cnt,
                           float* __restrict__ out)
{
    const int i = blockIdx.x * 256 + threadIdx.x;
    if (i < N_GRAPHS * HIDDEN) {
        const int g = i >> 7;
        out[i] = pool[i] / fmaxf(cnt[g], 1.0f);
    }
}

extern "C" void kernel_launch(void* const* d_in, const int* in_sizes, int n_in,
                              void* d_out, int out_size, void* d_ws, size_t ws_size,
                              hipStream_t stream)
{
    const float* x     = (const float*)d_in[0];
    const int*   ei    = (const int*)  d_in[1];
    const float* ea    = (const float*)d_in[2];
    const int*   batch = (const int*)  d_in[3];
    const float* W_in  = (const float*)d_in[4];
    const float* b_in  = (const float*)d_in[5];
    const float* W_msg = (const float*)d_in[6];
    const float* b_msg = (const float*)d_in[7];
    const float* W_up  = (const float*)d_in[8];
    const float* b_up  = (const float*)d_in[9];
    const float* gamma = (const float*)d_in[10];
    const float* beta  = (const float*)d_in[11];
    float* out = (float*)d_out;

    // ---- workspace layout ----
    float*   aggr  = (float*)d_ws;                                   // N*128 fp32 (102.4MB)
    ushortT* h16   = (ushortT*)(aggr + (size_t)N_NODES * HIDDEN);    // N*128 bf16 (51.2MB)
    ushortT* ea16  = h16 + (size_t)N_NODES * HIDDEN;                 // E*32 bf16 (38.4MB)
    ushortT* wmsgf = ea16 + (size_t)N_EDGES * 32;                    // 4*20480
    ushortT* wupf  = wmsgf + DEPTH * 20480;                          // 4*32768
    float*   bn_sum   = (float*)(wupf + DEPTH * 32768);              // 128
    float*   bn_sumsq = bn_sum + HIDDEN;                             // 128
    float*   bn_scale = bn_sumsq + HIDDEN;                           // 128
    float*   bn_shift = bn_scale + HIDDEN;                           // 128
    float*   pool     = bn_shift + HIDDEN;                           // G*128
    float*   cnt      = pool + (size_t)N_GRAPHS * HIDDEN;            // G

    // ---- one-time prep ----
    k_prep_ea<<<(N_EDGES * 32 + 255) / 256, 256, 0, stream>>>(ea, ea16);
    k_prep_wmsg<<<(DEPTH * 20480 + 255) / 256, 256, 0, stream>>>(W_msg, wmsgf);
    k_prep_wup<<<(DEPTH * 32768 + 255) / 256, 256, 0, stream>>>(W_up, wupf);
    k_input_proj<<<N_NODES / 8, 128, 0, stream>>>(x, W_in, b_in, h16);

    for (int d = 0; d < DEPTH; ++d) {
        hipMemsetAsync(aggr, 0, (size_t)N_NODES * HIDDEN * sizeof(float), stream);
        hipMemsetAsync(bn_sum, 0, 2 * HIDDEN * sizeof(float), stream);
        k_edge_mfma<<<N_EDGES / 64, 256, 0, stream>>>(
            h16, ei, ea16, wmsgf + (size_t)d * 20480, b_msg + (size_t)d * HIDDEN, aggr);
        k_update_mfma<<<N_NODES / 64, 256, 0, stream>>>(
            aggr, h16, wupf + (size_t)d * 32768, b_up + (size_t)d * HIDDEN,
            bn_sum, bn_sumsq);
        k_bn_finalize<<<1, 128, 0, stream>>>(bn_sum, bn_sumsq,
                                             gamma + (size_t)d * HIDDEN,
                                             beta + (size_t)d * HIDDEN,
                                             bn_scale, bn_shift);
        k_bn_norm<<<(N_NODES * HIDDEN / 4 + 255) / 256, 256, 0, stream>>>(
            aggr, bn_scale, bn_shift, h16);
    }

    hipMemsetAsync(pool, 0, ((size_t)N_GRAPHS * HIDDEN + N_GRAPHS) * sizeof(float), stream);
    k_pool_cnt<<<(N_NODES + 255) / 256, 256, 0, stream>>>(batch, cnt);
    k_pool_sum<<<N_NODES / 16, 128, 0, stream>>>(h16, batch, pool);
    k_pool_div<<<(N_GRAPHS * HIDDEN + 255) / 256, 256, 0, stream>>>(pool, cnt, out);
}

// Round 3
// 1739.360 us; speedup vs baseline: 2.4858x; 1.6084x over previous
//
#include <hip/hip_runtime.h>

#define N_NODES  200000
#define N_EDGES  600000
#define N_GRAPHS 4000
#define IN_DIM   25
#define EDGE_DIM 11
#define HIDDEN   128
#define DEPTH    4
#define BN_EPS   1e-5f

#define UB   32                 // nodes per block in update kernel
#define NBLK (N_NODES / UB)     // 6250 partial-stat rows

typedef unsigned short ushortT;
typedef __attribute__((ext_vector_type(8))) short short8v;
typedef __attribute__((ext_vector_type(4))) float float4v;

__device__ __forceinline__ float lrelu(float v) { return v > 0.f ? v : 0.1f * v; }

__device__ __forceinline__ ushortT f2bf(float f) {
    unsigned u = __builtin_bit_cast(unsigned, f);
    u = (u + 0x7fffu + ((u >> 16) & 1u)) >> 16;
    return (ushortT)u;
}
__device__ __forceinline__ float bf2f(ushortT h) {
    unsigned u = ((unsigned)h) << 16;
    return __builtin_bit_cast(float, u);
}

// ---------------- prep: edge_attr -> padded bf16 [N_EDGES][32] (cols 11..31 = 0) ----------------
__global__ __launch_bounds__(256) void k_prep_ea(const float* __restrict__ ea,
                                                 ushortT* __restrict__ ea16)
{
    const size_t i = (size_t)blockIdx.x * 256 + threadIdx.x;
    if (i >= (size_t)N_EDGES * 32) return;
    const int e = (int)(i >> 5), c = (int)(i & 31);
    ea16[i] = (c < EDGE_DIM) ? f2bf(ea[(size_t)e * EDGE_DIM + c]) : (ushortT)0;
}

// ---------------- prep: W_msg -> B-fragment layout, K padded 139->160 ----------------
__global__ __launch_bounds__(256) void k_prep_wmsg(const float* __restrict__ W,
                                                   ushortT* __restrict__ Wf)
{
    const int i = blockIdx.x * 256 + threadIdx.x;
    if (i >= DEPTH * 20480) return;
    const int d = i / 20480, r = i % 20480;
    const int j = r & 7, lane = (r >> 3) & 63, tile = r >> 9;
    const int ct = tile & 7, kt = tile >> 3;
    const int k = kt * 32 + ((lane >> 4) << 3) + j;
    const int c = ct * 16 + (lane & 15);
    Wf[i] = (k < HIDDEN + EDGE_DIM)
          ? f2bf(W[((size_t)d * (HIDDEN + EDGE_DIM) + k) * HIDDEN + c]) : (ushortT)0;
}

// ---------------- prep: W_up -> B-fragment layout, K = 256 ----------------
__global__ __launch_bounds__(256) void k_prep_wup(const float* __restrict__ W,
                                                  ushortT* __restrict__ Wf)
{
    const int i = blockIdx.x * 256 + threadIdx.x;
    if (i >= DEPTH * 32768) return;
    const int d = i / 32768, r = i % 32768;
    const int j = r & 7, lane = (r >> 3) & 63, tile = r >> 9;
    const int ct = tile & 7, kt = tile >> 3;
    const int k = kt * 32 + ((lane >> 4) << 3) + j;
    const int c = ct * 16 + (lane & 15);
    Wf[i] = f2bf(W[((size_t)d * 2 * HIDDEN + k) * HIDDEN + c]);
}

// ---------------- input projection: h16 = bf16(lrelu(x @ W_in + b_in)) ----------------
__global__ __launch_bounds__(128) void k_input_proj(const float* __restrict__ x,
                                                    const float* __restrict__ W,
                                                    const float* __restrict__ b,
                                                    ushortT* __restrict__ h16)
{
    const int t  = threadIdx.x;
    const int n0 = blockIdx.x * 8;
    __shared__ float sW[IN_DIM * HIDDEN];
    __shared__ float sx[8][IN_DIM];
    for (int i = t; i < IN_DIM * HIDDEN; i += 128) sW[i] = W[i];
    for (int i = t; i < 8 * IN_DIM; i += 128) {
        int n = i / IN_DIM, k = i % IN_DIM;
        sx[n][k] = x[(size_t)(n0 + n) * IN_DIM + k];
    }
    __syncthreads();
    const float bt = b[t];
    for (int n = 0; n < 8; ++n) {
        float acc = bt;
        #pragma unroll
        for (int k = 0; k < IN_DIM; ++k) acc += sx[n][k] * sW[k * HIDDEN + t];
        h16[(size_t)(n0 + n) * HIDDEN + t] = f2bf(lrelu(acc));
    }
}

// ------- fused edge message MFMA GEMM + lrelu + scatter-add -------
__global__ __launch_bounds__(256) void k_edge_mfma(const ushortT* __restrict__ h16,
                                                   const int*     __restrict__ ei,
                                                   const ushortT* __restrict__ ea16,
                                                   const ushortT* __restrict__ Wf,
                                                   const float*   __restrict__ bmsg,
                                                   float*         __restrict__ aggr)
{
    const int t    = threadIdx.x;
    const int wave = t >> 6, lane = t & 63;
    const int e0   = blockIdx.x * 64;

    __shared__ __align__(16) ushortT sA[64][168];
    __shared__ int sSrc[64];
    __shared__ int sDst[64];

    if (t < 64) { sSrc[t] = ei[e0 + t]; sDst[t] = ei[N_EDGES + e0 + t]; }
    __syncthreads();

    for (int i = t; i < 64 * 16; i += 256) {
        const int e = i >> 4, q = i & 15;
        const uint4 v = reinterpret_cast<const uint4*>(h16)[(size_t)sSrc[e] * 16 + q];
        *reinterpret_cast<uint4*>(&sA[e][q * 8]) = v;
    }
    for (int i = t; i < 64 * 4; i += 256) {
        const int e = i >> 2, q = i & 3;
        const uint4 v = reinterpret_cast<const uint4*>(ea16)[((size_t)(e0 + e)) * 4 + q];
        *reinterpret_cast<uint4*>(&sA[e][128 + q * 8]) = v;
    }
    __syncthreads();

    float4v acc[8];
    #pragma unroll
    for (int ct = 0; ct < 8; ++ct) acc[ct] = (float4v)(0.f);

    const int rowA = wave * 16 + (lane & 15);
    const int kOff = (lane >> 4) * 8;
    for (int kt = 0; kt < 5; ++kt) {
        const short8v a = *reinterpret_cast<const short8v*>(&sA[rowA][kt * 32 + kOff]);
        const short8v* wp = reinterpret_cast<const short8v*>(Wf) + (size_t)(kt * 8) * 64 + lane;
        #pragma unroll
        for (int ct = 0; ct < 8; ++ct) {
            const short8v bfr = wp[ct * 64];
            acc[ct] = __builtin_amdgcn_mfma_f32_16x16x32_bf16(a, bfr, acc[ct], 0, 0, 0);
        }
    }

    const int col = lane & 15;
    const int r0  = (lane >> 4) * 4;
    #pragma unroll
    for (int ct = 0; ct < 8; ++ct) {
        const float bt = bmsg[ct * 16 + col];
        #pragma unroll
        for (int j = 0; j < 4; ++j) {
            const int e = wave * 16 + r0 + j;
            const float v = lrelu(acc[ct][j] + bt);
            atomicAdd(&aggr[(size_t)sDst[e] * HIDDEN + ct * 16 + col], v);
        }
    }
}

// ------- update MFMA GEMM: relu(cat[aggr, h16] @ W_up + b_up) -------
// aggr staged as hi+lo bf16 split (fp32-accurate A operand); BN stats via
// block LDS reduction -> per-block partial stores (NO global atomics).
__global__ __launch_bounds__(128) void k_update_mfma(float*         __restrict__ aggr,
                                                     const ushortT* __restrict__ h16,
                                                     const ushortT* __restrict__ Wf,
                                                     const float*   __restrict__ bup,
                                                     float*         __restrict__ p_sum,
                                                     float*         __restrict__ p_sumsq)
{
    const int t    = threadIdx.x;
    const int wave = t >> 6, lane = t & 63;
    const int n0   = blockIdx.x * UB;

    __shared__ __align__(16) ushortT sA[UB][264];   // hi(aggr) cols 0..127, h16 cols 128..255
    __shared__ __align__(16) ushortT sLo[UB][136];  // lo(aggr)
    __shared__ float redS[2][HIDDEN];
    __shared__ float redQ[2][HIDDEN];

    // stage aggr fp32 -> hi/lo bf16 split
    for (int i = t; i < UB * 32; i += 128) {
        const int n = i >> 5, q = i & 31;
        const float4 v = reinterpret_cast<const float4*>(aggr)[(size_t)(n0 + n) * 32 + q];
        union { ushortT s[4]; uint2 u; } hi, lo;
        #pragma unroll
        for (int j = 0; j < 4; ++j) {
            const float f = (&v.x)[j];
            const ushortT hb = f2bf(f);
            hi.s[j] = hb;
            lo.s[j] = f2bf(f - bf2f(hb));
        }
        *reinterpret_cast<uint2*>(&sA[n][q * 4])  = hi.u;
        *reinterpret_cast<uint2*>(&sLo[n][q * 4]) = lo.u;
    }
    // stage h16 (cols 128..255)
    for (int i = t; i < UB * 16; i += 128) {
        const int n = i >> 4, q = i & 15;
        const uint4 v = reinterpret_cast<const uint4*>(h16)[(size_t)(n0 + n) * 16 + q];
        *reinterpret_cast<uint4*>(&sA[n][128 + q * 8]) = v;
    }
    __syncthreads();

    float4v acc[8];
    #pragma unroll
    for (int ct = 0; ct < 8; ++ct) acc[ct] = (float4v)(0.f);

    const int rowA = wave * 16 + (lane & 15);
    const int kOff = (lane >> 4) * 8;
    for (int kt = 0; kt < 8; ++kt) {
        const short8v a = *reinterpret_cast<const short8v*>(&sA[rowA][kt * 32 + kOff]);
        const short8v* wp = reinterpret_cast<const short8v*>(Wf) + (size_t)(kt * 8) * 64 + lane;
        #pragma unroll
        for (int ct = 0; ct < 8; ++ct) {
            const short8v bfr = wp[ct * 64];
            acc[ct] = __builtin_amdgcn_mfma_f32_16x16x32_bf16(a, bfr, acc[ct], 0, 0, 0);
        }
    }
    // lo correction over the aggr half (kt 0..3)
    for (int kt = 0; kt < 4; ++kt) {
        const short8v a = *reinterpret_cast<const short8v*>(&sLo[rowA][kt * 32 + kOff]);
        const short8v* wp = reinterpret_cast<const short8v*>(Wf) + (size_t)(kt * 8) * 64 + lane;
        #pragma unroll
        for (int ct = 0; ct < 8; ++ct) {
            const short8v bfr = wp[ct * 64];
            acc[ct] = __builtin_amdgcn_mfma_f32_16x16x32_bf16(a, bfr, acc[ct], 0, 0, 0);
        }
    }

    // epilogue: bias + relu, write fp32 in-place, per-wave stats -> LDS
    const int col = lane & 15;
    const int r0  = (lane >> 4) * 4;
    #pragma unroll
    for (int ct = 0; ct < 8; ++ct) {
        const float bt = bup[ct * 16 + col];
        float s = 0.f, q = 0.f;
        #pragma unroll
        for (int j = 0; j < 4; ++j) {
            const float v = fmaxf(acc[ct][j] + bt, 0.f);
            s += v; q += v * v;
            aggr[(size_t)(n0 + wave * 16 + r0 + j) * HIDDEN + ct * 16 + col] = v;
        }
        s += __shfl_xor(s, 16); s += __shfl_xor(s, 32);
        q += __shfl_xor(q, 16); q += __shfl_xor(q, 32);
        if (lane < 16) { redS[wave][ct * 16 + col] = s; redQ[wave][ct * 16 + col] = q; }
    }
    __syncthreads();
    if (t < HIDDEN) {
        p_sum  [(size_t)t * NBLK + blockIdx.x] = redS[0][t] + redS[1][t];
        p_sumsq[(size_t)t * NBLK + blockIdx.x] = redQ[0][t] + redQ[1][t];
    }
}

// ------- BN reduce: one block per feature, coalesced partial reduction -------
__global__ __launch_bounds__(256) void k_bn_reduce(const float* __restrict__ p_sum,
                                                   const float* __restrict__ p_sumsq,
                                                   const float* __restrict__ gamma,
                                                   const float* __restrict__ beta,
                                                   float* __restrict__ scale,
                                                   float* __restrict__ shift)
{
    const int c = blockIdx.x, t = threadIdx.x;
    float s = 0.f, q = 0.f;
    for (int i = t; i < NBLK; i += 256) {
        s += p_sum  [(size_t)c * NBLK + i];
        q += p_sumsq[(size_t)c * NBLK + i];
    }
    #pragma unroll
    for (int off = 32; off > 0; off >>= 1) {
        s += __shfl_down(s, off);
        q += __shfl_down(q, off);
    }
    __shared__ float ls[4], lq[4];
    const int w = t >> 6;
    if ((t & 63) == 0) { ls[w] = s; lq[w] = q; }
    __syncthreads();
    if (t == 0) {
        s = ls[0] + ls[1] + ls[2] + ls[3];
        q = lq[0] + lq[1] + lq[2] + lq[3];
        const float mu  = s * (1.f / N_NODES);
        const float var = q * (1.f / N_NODES) - mu * mu;
        const float sc  = gamma[c] * rsqrtf(var + BN_EPS);
        scale[c] = sc;
        shift[c] = beta[c] - mu * sc;
    }
}

// ------- BN normalize: buf fp32 -> h16 bf16 -------
__global__ __launch_bounds__(256) void k_bn_norm(const float* __restrict__ buf,
                                                 const float* __restrict__ scale,
                                                 const float* __restrict__ shift,
                                                 ushortT* __restrict__ h16)
{
    const size_t i = (size_t)blockIdx.x * 256 + threadIdx.x;
    if (i >= (size_t)N_NODES * HIDDEN / 4) return;
    const float4 v = reinterpret_cast<const float4*>(buf)[i];
    const int c0 = (int)((i * 4) & (HIDDEN - 1));
    union { ushortT s[4]; uint2 u; } p;
    p.s[0] = f2bf(v.x * scale[c0 + 0] + shift[c0 + 0]);
    p.s[1] = f2bf(v.y * scale[c0 + 1] + shift[c0 + 1]);
    p.s[2] = f2bf(v.z * scale[c0 + 2] + shift[c0 + 2]);
    p.s[3] = f2bf(v.w * scale[c0 + 3] + shift[c0 + 3]);
    reinterpret_cast<uint2*>(h16)[i] = p.u;
}

// ------- mean pool over graphs -------
__global__ void k_pool_cnt(const int* __restrict__ batch, float* __restrict__ cnt)
{
    const int n = blockIdx.x * 256 + threadIdx.x;
    if (n < N_NODES) atomicAdd(&cnt[batch[n]], 1.0f);
}

__global__ __launch_bounds__(128) void k_pool_sum(const ushortT* __restrict__ h16,
                                                  const int* __restrict__ batch,
                                                  float* __restrict__ pool)
{
    const int t  = threadIdx.x;
    const int n0 = blockIdx.x * 16;
    __shared__ int sb[16];
    if (t < 16) sb[t] = batch[n0 + t];
    __syncthreads();
    int g = sb[0];
    float acc = 0.f;
    for (int j = 0; j < 16; ++j) {
        const float v = bf2f(h16[(size_t)(n0 + j) * HIDDEN + t]);
        if (sb[j] != g) {
            atomicAdd(&pool[(size_t)g * HIDDEN + t], acc);
            g = sb[j];
            acc = v;
        } else {
            acc += v;
        }
    }
    atomicAdd(&pool[(size_t)g * HIDDEN + t], acc);
}

__global__ void k_pool_div(const float* __restrict__ pool,
                           const float* __restrict__ cnt,
                           float* __restrict__ out)
{
    const int i = blockIdx.x * 256 + threadIdx.x;
    if (i < N_GRAPHS * HIDDEN) {
        const int g = i >> 7;
        out[i] = pool[i] / fmaxf(cnt[g], 1.0f);
    }
}

extern "C" void kernel_launch(void* const* d_in, const int* in_sizes, int n_in,
                              void* d_out, int out_size, void* d_ws, size_t ws_size,
                              hipStream_t stream)
{
    const float* x     = (const float*)d_in[0];
    const int*   ei    = (const int*)  d_in[1];
    const float* ea    = (const float*)d_in[2];
    const int*   batch = (const int*)  d_in[3];
    const float* W_in  = (const float*)d_in[4];
    const float* b_in  = (const float*)d_in[5];
    const float* W_msg = (const float*)d_in[6];
    const float* b_msg = (const float*)d_in[7];
    const float* W_up  = (const float*)d_in[8];
    const float* b_up  = (const float*)d_in[9];
    const float* gamma = (const float*)d_in[10];
    const float* beta  = (const float*)d_in[11];
    float* out = (float*)d_out;

    // ---- workspace layout ----
    float*   aggr  = (float*)d_ws;                                   // N*128 fp32
    ushortT* h16   = (ushortT*)(aggr + (size_t)N_NODES * HIDDEN);    // N*128 bf16
    ushortT* ea16  = h16 + (size_t)N_NODES * HIDDEN;                 // E*32 bf16
    ushortT* wmsgf = ea16 + (size_t)N_EDGES * 32;                    // 4*20480
    ushortT* wupf  = wmsgf + DEPTH * 20480;                          // 4*32768
    float*   bn_scale = (float*)(wupf + DEPTH * 32768);              // 128
    float*   bn_shift = bn_scale + HIDDEN;                           // 128
    float*   pool     = bn_shift + HIDDEN;                           // G*128
    float*   cnt      = pool + (size_t)N_GRAPHS * HIDDEN;            // G
    float*   p_sum    = cnt + N_GRAPHS;                              // 128*NBLK
    float*   p_sumsq  = p_sum + (size_t)HIDDEN * NBLK;               // 128*NBLK

    // ---- one-time prep ----
    k_prep_ea<<<(N_EDGES * 32 + 255) / 256, 256, 0, stream>>>(ea, ea16);
    k_prep_wmsg<<<(DEPTH * 20480 + 255) / 256, 256, 0, stream>>>(W_msg, wmsgf);
    k_prep_wup<<<(DEPTH * 32768 + 255) / 256, 256, 0, stream>>>(W_up, wupf);
    k_input_proj<<<N_NODES / 8, 128, 0, stream>>>(x, W_in, b_in, h16);

    for (int d = 0; d < DEPTH; ++d) {
        hipMemsetAsync(aggr, 0, (size_t)N_NODES * HIDDEN * sizeof(float), stream);
        k_edge_mfma<<<N_EDGES / 64, 256, 0, stream>>>(
            h16, ei, ea16, wmsgf + (size_t)d * 20480, b_msg + (size_t)d * HIDDEN, aggr);
        k_update_mfma<<<N_NODES / UB, 128, 0, stream>>>(
            aggr, h16, wupf + (size_t)d * 32768, b_up + (size_t)d * HIDDEN,
            p_sum, p_sumsq);
        k_bn_reduce<<<HIDDEN, 256, 0, stream>>>(p_sum, p_sumsq,
                                                gamma + (size_t)d * HIDDEN,
                                                beta + (size_t)d * HIDDEN,
                                                bn_scale, bn_shift);
        k_bn_norm<<<(N_NODES * HIDDEN / 4 + 255) / 256, 256, 0, stream>>>(
            aggr, bn_scale, bn_shift, h16);
    }

    hipMemsetAsync(pool, 0, ((size_t)N_GRAPHS * HIDDEN + N_GRAPHS) * sizeof(float), stream);
    k_pool_cnt<<<(N_NODES + 255) / 256, 256, 0, stream>>>(batch, cnt);
    k_pool_sum<<<N_NODES / 16, 128, 0, stream>>>(h16, batch, pool);
    k_pool_div<<<(N_GRAPHS * HIDDEN + 255) / 256, 256, 0, stream>>>(pool, cnt, out);
}

// Round 4
// 1166.808 us; speedup vs baseline: 3.7055x; 1.4907x over previous
//
#include <hip/hip_runtime.h>

#define N_NODES  200000
#define N_EDGES  600000
#define N_GRAPHS 4000
#define IN_DIM   25
#define EDGE_DIM 11
#define HIDDEN   128
#define DEPTH    4
#define BN_EPS   1e-5f

#define UB   32                 // nodes per block in update kernel
#define NBLK (N_NODES / UB)     // partial-stat rows
#define CHUNK  256
#define NCHUNK ((N_NODES + CHUNK - 1) / CHUNK)   // 782

typedef unsigned short ushortT;
typedef __attribute__((ext_vector_type(8))) short short8v;
typedef __attribute__((ext_vector_type(4))) float float4v;

__device__ __forceinline__ float lrelu(float v) { return v > 0.f ? v : 0.1f * v; }

__device__ __forceinline__ ushortT f2bf(float f) {
    unsigned u = __builtin_bit_cast(unsigned, f);
    u = (u + 0x7fffu + ((u >> 16) & 1u)) >> 16;
    return (ushortT)u;
}
__device__ __forceinline__ float bf2f(ushortT h) {
    unsigned u = ((unsigned)h) << 16;
    return __builtin_bit_cast(float, u);
}

// ================= counting sort of edges by dst (once per call) =================
__global__ void k_hist(const int* __restrict__ ei, int* __restrict__ cnt)
{
    const int e = blockIdx.x * 256 + threadIdx.x;
    if (e < N_EDGES) atomicAdd(&cnt[ei[N_EDGES + e]], 1);
}

__global__ __launch_bounds__(256) void k_chunk_sum(const int* __restrict__ cnt,
                                                   int* __restrict__ bsum)
{
    const int t = threadIdx.x;
    const int i = blockIdx.x * CHUNK + t;
    int v = (i < N_NODES) ? cnt[i] : 0;
    #pragma unroll
    for (int off = 32; off > 0; off >>= 1) v += __shfl_down(v, off);
    __shared__ int ws[4];
    if ((t & 63) == 0) ws[t >> 6] = v;
    __syncthreads();
    if (t == 0) bsum[blockIdx.x] = ws[0] + ws[1] + ws[2] + ws[3];
}

__global__ __launch_bounds__(1024) void k_scan_bsums(const int* __restrict__ bsum,
                                                     int* __restrict__ bscan)
{
    __shared__ int s[1024];
    const int t = threadIdx.x;
    const int v = (t < NCHUNK) ? bsum[t] : 0;
    s[t] = v; __syncthreads();
    for (int off = 1; off < 1024; off <<= 1) {
        const int x = (t >= off) ? s[t - off] : 0;
        __syncthreads();
        s[t] += x;
        __syncthreads();
    }
    if (t < NCHUNK) bscan[t] = s[t] - v;   // exclusive
}

__global__ __launch_bounds__(256) void k_chunk_scan(const int* __restrict__ cnt,
                                                    const int* __restrict__ bscan,
                                                    int* __restrict__ off_work)
{
    __shared__ int s[CHUNK];
    const int b = blockIdx.x, t = threadIdx.x;
    const int i = b * CHUNK + t;
    const int v = (i < N_NODES) ? cnt[i] : 0;
    s[t] = v; __syncthreads();
    for (int off = 1; off < CHUNK; off <<= 1) {
        const int x = (t >= off) ? s[t - off] : 0;
        __syncthreads();
        s[t] += x;
        __syncthreads();
    }
    if (i < N_NODES) off_work[i] = bscan[b] + s[t] - v;   // exclusive
}

__global__ void k_scatter(const int* __restrict__ ei, int* __restrict__ off_work,
                          int* __restrict__ srcS, int* __restrict__ dstS,
                          int* __restrict__ perm)
{
    const int e = blockIdx.x * 256 + threadIdx.x;
    if (e < N_EDGES) {
        const int d = ei[N_EDGES + e];
        const int pos = atomicAdd(&off_work[d], 1);
        srcS[pos] = ei[e];
        dstS[pos] = d;
        perm[pos] = e;
    }
}

// ---------------- prep: edge_attr (sorted order) -> padded bf16 [N_EDGES][32] ----------------
__global__ __launch_bounds__(256) void k_prep_ea(const float* __restrict__ ea,
                                                 const int* __restrict__ perm,
                                                 ushortT* __restrict__ ea16)
{
    const size_t i = (size_t)blockIdx.x * 256 + threadIdx.x;
    if (i >= (size_t)N_EDGES * 32) return;
    const int e = (int)(i >> 5), c = (int)(i & 31);
    const int pe = perm[e];
    ea16[i] = (c < EDGE_DIM) ? f2bf(ea[(size_t)pe * EDGE_DIM + c]) : (ushortT)0;
}

// ---------------- prep: W_msg -> B-fragment layout, K padded 139->160 ----------------
__global__ __launch_bounds__(256) void k_prep_wmsg(const float* __restrict__ W,
                                                   ushortT* __restrict__ Wf)
{
    const int i = blockIdx.x * 256 + threadIdx.x;
    if (i >= DEPTH * 20480) return;
    const int d = i / 20480, r = i % 20480;
    const int j = r & 7, lane = (r >> 3) & 63, tile = r >> 9;
    const int ct = tile & 7, kt = tile >> 3;
    const int k = kt * 32 + ((lane >> 4) << 3) + j;
    const int c = ct * 16 + (lane & 15);
    Wf[i] = (k < HIDDEN + EDGE_DIM)
          ? f2bf(W[((size_t)d * (HIDDEN + EDGE_DIM) + k) * HIDDEN + c]) : (ushortT)0;
}

// ---------------- prep: W_up -> B-fragment layout, K = 256 ----------------
__global__ __launch_bounds__(256) void k_prep_wup(const float* __restrict__ W,
                                                  ushortT* __restrict__ Wf)
{
    const int i = blockIdx.x * 256 + threadIdx.x;
    if (i >= DEPTH * 32768) return;
    const int d = i / 32768, r = i % 32768;
    const int j = r & 7, lane = (r >> 3) & 63, tile = r >> 9;
    const int ct = tile & 7, kt = tile >> 3;
    const int k = kt * 32 + ((lane >> 4) << 3) + j;
    const int c = ct * 16 + (lane & 15);
    Wf[i] = f2bf(W[((size_t)d * 2 * HIDDEN + k) * HIDDEN + c]);
}

// ---------------- input projection: h16 = bf16(lrelu(x @ W_in + b_in)) ----------------
__global__ __launch_bounds__(128) void k_input_proj(const float* __restrict__ x,
                                                    const float* __restrict__ W,
                                                    const float* __restrict__ b,
                                                    ushortT* __restrict__ h16)
{
    const int t  = threadIdx.x;
    const int n0 = blockIdx.x * 8;
    __shared__ float sW[IN_DIM * HIDDEN];
    __shared__ float sx[8][IN_DIM];
    for (int i = t; i < IN_DIM * HIDDEN; i += 128) sW[i] = W[i];
    for (int i = t; i < 8 * IN_DIM; i += 128) {
        int n = i / IN_DIM, k = i % IN_DIM;
        sx[n][k] = x[(size_t)(n0 + n) * IN_DIM + k];
    }
    __syncthreads();
    const float bt = b[t];
    for (int n = 0; n < 8; ++n) {
        float acc = bt;
        #pragma unroll
        for (int k = 0; k < IN_DIM; ++k) acc += sx[n][k] * sW[k * HIDDEN + t];
        h16[(size_t)(n0 + n) * HIDDEN + t] = f2bf(lrelu(acc));
    }
}

// ------- fused edge message MFMA GEMM + lrelu + segmented-reduce scatter -------
// Edges are SORTED BY DST. Interior runs -> plain coalesced stores; boundary runs -> atomicAdd.
__global__ __launch_bounds__(256) void k_edge_mfma(const ushortT* __restrict__ h16,
                                                   const int*     __restrict__ srcS,
                                                   const int*     __restrict__ dstS,
                                                   const ushortT* __restrict__ ea16,
                                                   const ushortT* __restrict__ Wf,
                                                   const float*   __restrict__ bmsg,
                                                   float*         __restrict__ aggr)
{
    const int t    = threadIdx.x;
    const int wave = t >> 6, lane = t & 63;
    const int e0   = blockIdx.x * 64;

    // sA (bf16 A-tile, 21504B) and sMsg (fp32 messages, 33792B) alias the same LDS
    __shared__ __align__(16) unsigned char smem[64 * 132 * 4];
    ushortT (*sA)[168]  = reinterpret_cast<ushortT (*)[168]>(smem);
    float   (*sMsg)[132] = reinterpret_cast<float (*)[132]>(smem);
    __shared__ int sSrc[64];
    __shared__ int sDst[64];

    if (t < 64) { sSrc[t] = srcS[e0 + t]; sDst[t] = dstS[e0 + t]; }
    __syncthreads();

    // stage h16 rows: 64 edges x 16 uint4
    for (int i = t; i < 64 * 16; i += 256) {
        const int e = i >> 4, q = i & 15;
        const uint4 v = reinterpret_cast<const uint4*>(h16)[(size_t)sSrc[e] * 16 + q];
        *reinterpret_cast<uint4*>(&sA[e][q * 8]) = v;
    }
    // stage padded edge_attr (sorted -> contiguous): 64 edges x 4 uint4
    for (int i = t; i < 64 * 4; i += 256) {
        const int e = i >> 2, q = i & 3;
        const uint4 v = reinterpret_cast<const uint4*>(ea16)[((size_t)(e0 + e)) * 4 + q];
        *reinterpret_cast<uint4*>(&sA[e][128 + q * 8]) = v;
    }
    __syncthreads();

    float4v acc[8];
    #pragma unroll
    for (int ct = 0; ct < 8; ++ct) acc[ct] = (float4v)(0.f);

    const int rowA = wave * 16 + (lane & 15);
    const int kOff = (lane >> 4) * 8;
    for (int kt = 0; kt < 5; ++kt) {
        const short8v a = *reinterpret_cast<const short8v*>(&sA[rowA][kt * 32 + kOff]);
        const short8v* wp = reinterpret_cast<const short8v*>(Wf) + (size_t)(kt * 8) * 64 + lane;
        #pragma unroll
        for (int ct = 0; ct < 8; ++ct) {
            const short8v bfr = wp[ct * 64];
            acc[ct] = __builtin_amdgcn_mfma_f32_16x16x32_bf16(a, bfr, acc[ct], 0, 0, 0);
        }
    }
    __syncthreads();   // done reading sA; safe to overwrite with sMsg

    // bias + lrelu -> LDS message tile
    const int col = lane & 15;
    const int r0  = (lane >> 4) * 4;
    #pragma unroll
    for (int ct = 0; ct < 8; ++ct) {
        const float bt = bmsg[ct * 16 + col];
        #pragma unroll
        for (int j = 0; j < 4; ++j) {
            sMsg[wave * 16 + r0 + j][ct * 16 + col] = lrelu(acc[ct][j] + bt);
        }
    }
    __syncthreads();

    // column-parallel segmented reduction over each 32-edge half
    const int half = t >> 7;          // waves 0,1 -> half 0; waves 2,3 -> half 1
    const int c    = t & 127;
    const int base = half * 32;
    float a = 0.f;
    int cur = sDst[base];
    bool atStart = true;              // current run may extend before this half
    for (int e = base; e < base + 32; ++e) {
        const int d = sDst[e];
        if (d != cur) {
            if (atStart) atomicAdd(&aggr[(size_t)cur * HIDDEN + c], a);
            else         aggr[(size_t)cur * HIDDEN + c] = a;   // run fully interior: complete sum
            atStart = false; cur = d; a = 0.f;
        }
        a += sMsg[e][c];
    }
    atomicAdd(&aggr[(size_t)cur * HIDDEN + c], a);   // final run may continue past half
}

// ------- update MFMA GEMM: relu(cat[aggr, h16] @ W_up + b_up) -------
__global__ __launch_bounds__(128) void k_update_mfma(float*         __restrict__ aggr,
                                                     const ushortT* __restrict__ h16,
                                                     const ushortT* __restrict__ Wf,
                                                     const float*   __restrict__ bup,
                                                     float*         __restrict__ p_sum,
                                                     float*         __restrict__ p_sumsq)
{
    const int t    = threadIdx.x;
    const int wave = t >> 6, lane = t & 63;
    const int n0   = blockIdx.x * UB;

    __shared__ __align__(16) ushortT sA[UB][264];
    __shared__ __align__(16) ushortT sLo[UB][136];
    __shared__ float redS[2][HIDDEN];
    __shared__ float redQ[2][HIDDEN];

    for (int i = t; i < UB * 32; i += 128) {
        const int n = i >> 5, q = i & 31;
        const float4 v = reinterpret_cast<const float4*>(aggr)[(size_t)(n0 + n) * 32 + q];
        union { ushortT s[4]; uint2 u; } hi, lo;
        #pragma unroll
        for (int j = 0; j < 4; ++j) {
            const float f = (&v.x)[j];
            const ushortT hb = f2bf(f);
            hi.s[j] = hb;
            lo.s[j] = f2bf(f - bf2f(hb));
        }
        *reinterpret_cast<uint2*>(&sA[n][q * 4])  = hi.u;
        *reinterpret_cast<uint2*>(&sLo[n][q * 4]) = lo.u;
    }
    for (int i = t; i < UB * 16; i += 128) {
        const int n = i >> 4, q = i & 15;
        const uint4 v = reinterpret_cast<const uint4*>(h16)[(size_t)(n0 + n) * 16 + q];
        *reinterpret_cast<uint4*>(&sA[n][128 + q * 8]) = v;
    }
    __syncthreads();

    float4v acc[8];
    #pragma unroll
    for (int ct = 0; ct < 8; ++ct) acc[ct] = (float4v)(0.f);

    const int rowA = wave * 16 + (lane & 15);
    const int kOff = (lane >> 4) * 8;
    for (int kt = 0; kt < 8; ++kt) {
        const short8v a = *reinterpret_cast<const short8v*>(&sA[rowA][kt * 32 + kOff]);
        const short8v* wp = reinterpret_cast<const short8v*>(Wf) + (size_t)(kt * 8) * 64 + lane;
        #pragma unroll
        for (int ct = 0; ct < 8; ++ct) {
            const short8v bfr = wp[ct * 64];
            acc[ct] = __builtin_amdgcn_mfma_f32_16x16x32_bf16(a, bfr, acc[ct], 0, 0, 0);
        }
    }
    for (int kt = 0; kt < 4; ++kt) {
        const short8v a = *reinterpret_cast<const short8v*>(&sLo[rowA][kt * 32 + kOff]);
        const short8v* wp = reinterpret_cast<const short8v*>(Wf) + (size_t)(kt * 8) * 64 + lane;
        #pragma unroll
        for (int ct = 0; ct < 8; ++ct) {
            const short8v bfr = wp[ct * 64];
            acc[ct] = __builtin_amdgcn_mfma_f32_16x16x32_bf16(a, bfr, acc[ct], 0, 0, 0);
        }
    }

    const int col = lane & 15;
    const int r0  = (lane >> 4) * 4;
    #pragma unroll
    for (int ct = 0; ct < 8; ++ct) {
        const float bt = bup[ct * 16 + col];
        float s = 0.f, q = 0.f;
        #pragma unroll
        for (int j = 0; j < 4; ++j) {
            const float v = fmaxf(acc[ct][j] + bt, 0.f);
            s += v; q += v * v;
            aggr[(size_t)(n0 + wave * 16 + r0 + j) * HIDDEN + ct * 16 + col] = v;
        }
        s += __shfl_xor(s, 16); s += __shfl_xor(s, 32);
        q += __shfl_xor(q, 16); q += __shfl_xor(q, 32);
        if (lane < 16) { redS[wave][ct * 16 + col] = s; redQ[wave][ct * 16 + col] = q; }
    }
    __syncthreads();
    if (t < HIDDEN) {
        p_sum  [(size_t)t * NBLK + blockIdx.x] = redS[0][t] + redS[1][t];
        p_sumsq[(size_t)t * NBLK + blockIdx.x] = redQ[0][t] + redQ[1][t];
    }
}

// ------- BN reduce: one block per feature -------
__global__ __launch_bounds__(256) void k_bn_reduce(const float* __restrict__ p_sum,
                                                   const float* __restrict__ p_sumsq,
                                                   const float* __restrict__ gamma,
                                                   const float* __restrict__ beta,
                                                   float* __restrict__ scale,
                                                   float* __restrict__ shift)
{
    const int c = blockIdx.x, t = threadIdx.x;
    float s = 0.f, q = 0.f;
    for (int i = t; i < NBLK; i += 256) {
        s += p_sum  [(size_t)c * NBLK + i];
        q += p_sumsq[(size_t)c * NBLK + i];
    }
    #pragma unroll
    for (int off = 32; off > 0; off >>= 1) {
        s += __shfl_down(s, off);
        q += __shfl_down(q, off);
    }
    __shared__ float ls[4], lq[4];
    const int w = t >> 6;
    if ((t & 63) == 0) { ls[w] = s; lq[w] = q; }
    __syncthreads();
    if (t == 0) {
        s = ls[0] + ls[1] + ls[2] + ls[3];
        q = lq[0] + lq[1] + lq[2] + lq[3];
        const float mu  = s * (1.f / N_NODES);
        const float var = q * (1.f / N_NODES) - mu * mu;
        const float sc  = gamma[c] * rsqrtf(var + BN_EPS);
        scale[c] = sc;
        shift[c] = beta[c] - mu * sc;
    }
}

// ------- BN normalize: buf fp32 -> h16 bf16 -------
__global__ __launch_bounds__(256) void k_bn_norm(const float* __restrict__ buf,
                                                 const float* __restrict__ scale,
                                                 const float* __restrict__ shift,
                                                 ushortT* __restrict__ h16)
{
    const size_t i = (size_t)blockIdx.x * 256 + threadIdx.x;
    if (i >= (size_t)N_NODES * HIDDEN / 4) return;
    const float4 v = reinterpret_cast<const float4*>(buf)[i];
    const int c0 = (int)((i * 4) & (HIDDEN - 1));
    union { ushortT s[4]; uint2 u; } p;
    p.s[0] = f2bf(v.x * scale[c0 + 0] + shift[c0 + 0]);
    p.s[1] = f2bf(v.y * scale[c0 + 1] + shift[c0 + 1]);
    p.s[2] = f2bf(v.z * scale[c0 + 2] + shift[c0 + 2]);
    p.s[3] = f2bf(v.w * scale[c0 + 3] + shift[c0 + 3]);
    reinterpret_cast<uint2*>(h16)[i] = p.u;
}

// ------- mean pool over graphs -------
__global__ void k_pool_cnt(const int* __restrict__ batch, float* __restrict__ cnt)
{
    const int n = blockIdx.x * 256 + threadIdx.x;
    if (n < N_NODES) atomicAdd(&cnt[batch[n]], 1.0f);
}

__global__ __launch_bounds__(128) void k_pool_sum(const ushortT* __restrict__ h16,
                                                  const int* __restrict__ batch,
                                                  float* __restrict__ pool)
{
    const int t  = threadIdx.x;
    const int n0 = blockIdx.x * 16;
    __shared__ int sb[16];
    if (t < 16) sb[t] = batch[n0 + t];
    __syncthreads();
    int g = sb[0];
    float acc = 0.f;
    for (int j = 0; j < 16; ++j) {
        const float v = bf2f(h16[(size_t)(n0 + j) * HIDDEN + t]);
        if (sb[j] != g) {
            atomicAdd(&pool[(size_t)g * HIDDEN + t], acc);
            g = sb[j];
            acc = v;
        } else {
            acc += v;
        }
    }
    atomicAdd(&pool[(size_t)g * HIDDEN + t], acc);
}

__global__ void k_pool_div(const float* __restrict__ pool,
                           const float* __restrict__ cnt,
                           float* __restrict__ out)
{
    const int i = blockIdx.x * 256 + threadIdx.x;
    if (i < N_GRAPHS * HIDDEN) {
        const int g = i >> 7;
        out[i] = pool[i] / fmaxf(cnt[g], 1.0f);
    }
}

extern "C" void kernel_launch(void* const* d_in, const int* in_sizes, int n_in,
                              void* d_out, int out_size, void* d_ws, size_t ws_size,
                              hipStream_t stream)
{
    const float* x     = (const float*)d_in[0];
    const int*   ei    = (const int*)  d_in[1];
    const float* ea    = (const float*)d_in[2];
    const int*   batch = (const int*)  d_in[3];
    const float* W_in  = (const float*)d_in[4];
    const float* b_in  = (const float*)d_in[5];
    const float* W_msg = (const float*)d_in[6];
    const float* b_msg = (const float*)d_in[7];
    const float* W_up  = (const float*)d_in[8];
    const float* b_up  = (const float*)d_in[9];
    const float* gamma = (const float*)d_in[10];
    const float* beta  = (const float*)d_in[11];
    float* out = (float*)d_out;

    // ---- workspace layout ----
    float*   aggr  = (float*)d_ws;                                   // N*128 fp32
    ushortT* h16   = (ushortT*)(aggr + (size_t)N_NODES * HIDDEN);    // N*128 bf16
    ushortT* ea16  = h16 + (size_t)N_NODES * HIDDEN;                 // E*32 bf16
    ushortT* wmsgf = ea16 + (size_t)N_EDGES * 32;                    // 4*20480
    ushortT* wupf  = wmsgf + DEPTH * 20480;                          // 4*32768
    float*   bn_scale = (float*)(wupf + DEPTH * 32768);              // 128
    float*   bn_shift = bn_scale + HIDDEN;                           // 128
    float*   pool     = bn_shift + HIDDEN;                           // G*128
    float*   cnt      = pool + (size_t)N_GRAPHS * HIDDEN;            // G
    float*   p_sum    = cnt + N_GRAPHS;                              // 128*NBLK
    float*   p_sumsq  = p_sum + (size_t)HIDDEN * NBLK;               // 128*NBLK
    int*     ecnt     = (int*)(p_sumsq + (size_t)HIDDEN * NBLK);     // N
    int*     off_work = ecnt + N_NODES;                              // N
    int*     bsum     = off_work + N_NODES;                          // NCHUNK
    int*     bscan    = bsum + 1024;                                 // NCHUNK
    int*     srcS     = bscan + 1024;                                // E
    int*     dstS     = srcS + N_EDGES;                              // E
    int*     perm     = dstS + N_EDGES;                              // E

    // ---- edge sort by dst (once; edge_index constant across layers) ----
    hipMemsetAsync(ecnt, 0, N_NODES * sizeof(int), stream);
    k_hist<<<(N_EDGES + 255) / 256, 256, 0, stream>>>(ei, ecnt);
    k_chunk_sum<<<NCHUNK, 256, 0, stream>>>(ecnt, bsum);
    k_scan_bsums<<<1, 1024, 0, stream>>>(bsum, bscan);
    k_chunk_scan<<<NCHUNK, 256, 0, stream>>>(ecnt, bscan, off_work);
    k_scatter<<<(N_EDGES + 255) / 256, 256, 0, stream>>>(ei, off_work, srcS, dstS, perm);

    // ---- one-time prep ----
    k_prep_ea<<<(N_EDGES * 32 + 255) / 256, 256, 0, stream>>>(ea, perm, ea16);
    k_prep_wmsg<<<(DEPTH * 20480 + 255) / 256, 256, 0, stream>>>(W_msg, wmsgf);
    k_prep_wup<<<(DEPTH * 32768 + 255) / 256, 256, 0, stream>>>(W_up, wupf);
    k_input_proj<<<N_NODES / 8, 128, 0, stream>>>(x, W_in, b_in, h16);

    for (int d = 0; d < DEPTH; ++d) {
        hipMemsetAsync(aggr, 0, (size_t)N_NODES * HIDDEN * sizeof(float), stream);
        k_edge_mfma<<<N_EDGES / 64, 256, 0, stream>>>(
            h16, srcS, dstS, ea16, wmsgf + (size_t)d * 20480,
            b_msg + (size_t)d * HIDDEN, aggr);
        k_update_mfma<<<N_NODES / UB, 128, 0, stream>>>(
            aggr, h16, wupf + (size_t)d * 32768, b_up + (size_t)d * HIDDEN,
            p_sum, p_sumsq);
        k_bn_reduce<<<HIDDEN, 256, 0, stream>>>(p_sum, p_sumsq,
                                                gamma + (size_t)d * HIDDEN,
                                                beta + (size_t)d * HIDDEN,
                                                bn_scale, bn_shift);
        k_bn_norm<<<(N_NODES * HIDDEN / 4 + 255) / 256, 256, 0, stream>>>(
            aggr, bn_scale, bn_shift, h16);
    }

    hipMemsetAsync(pool, 0, ((size_t)N_GRAPHS * HIDDEN + N_GRAPHS) * sizeof(float), stream);
    k_pool_cnt<<<(N_NODES + 255) / 256, 256, 0, stream>>>(batch, cnt);
    k_pool_sum<<<N_NODES / 16, 128, 0, stream>>>(h16, batch, pool);
    k_pool_div<<<(N_GRAPHS * HIDDEN + 255) / 256, 256, 0, stream>>>(pool, cnt, out);
}

// Round 5
// 937.045 us; speedup vs baseline: 4.6141x; 1.2452x over previous
//
#include <hip/hip_runtime.h>

#define N_NODES  200000
#define N_EDGES  600000
#define N_GRAPHS 4000
#define IN_DIM   25
#define EDGE_DIM 11
#define HIDDEN   128
#define DEPTH    4
#define BN_EPS   1e-5f

#define UB   32                 // nodes per block in update kernel
#define NBLK (N_NODES / UB)     // partial-stat rows
#define CHUNK  256
#define NCHUNK ((N_NODES + CHUNK - 1) / CHUNK)   // 782

typedef unsigned short ushortT;
typedef __attribute__((ext_vector_type(8))) short short8v;
typedef __attribute__((ext_vector_type(4))) float float4v;

__device__ __forceinline__ float lrelu(float v) { return v > 0.f ? v : 0.1f * v; }

__device__ __forceinline__ ushortT f2bf(float f) {
    unsigned u = __builtin_bit_cast(unsigned, f);
    u = (u + 0x7fffu + ((u >> 16) & 1u)) >> 16;
    return (ushortT)u;
}
__device__ __forceinline__ float bf2f(ushortT h) {
    unsigned u = ((unsigned)h) << 16;
    return __builtin_bit_cast(float, u);
}

// ================= counting sort of edges by dst (once per call) =================
__global__ void k_hist(const int* __restrict__ ei, int* __restrict__ cnt)
{
    const int e = blockIdx.x * 256 + threadIdx.x;
    if (e < N_EDGES) atomicAdd(&cnt[ei[N_EDGES + e]], 1);
}

__global__ __launch_bounds__(256) void k_chunk_sum(const int* __restrict__ cnt,
                                                   int* __restrict__ bsum)
{
    const int t = threadIdx.x;
    const int i = blockIdx.x * CHUNK + t;
    int v = (i < N_NODES) ? cnt[i] : 0;
    #pragma unroll
    for (int off = 32; off > 0; off >>= 1) v += __shfl_down(v, off);
    __shared__ int ws[4];
    if ((t & 63) == 0) ws[t >> 6] = v;
    __syncthreads();
    if (t == 0) bsum[blockIdx.x] = ws[0] + ws[1] + ws[2] + ws[3];
}

__global__ __launch_bounds__(1024) void k_scan_bsums(const int* __restrict__ bsum,
                                                     int* __restrict__ bscan)
{
    __shared__ int s[1024];
    const int t = threadIdx.x;
    const int v = (t < NCHUNK) ? bsum[t] : 0;
    s[t] = v; __syncthreads();
    for (int off = 1; off < 1024; off <<= 1) {
        const int x = (t >= off) ? s[t - off] : 0;
        __syncthreads();
        s[t] += x;
        __syncthreads();
    }
    if (t < NCHUNK) bscan[t] = s[t] - v;   // exclusive
}

__global__ __launch_bounds__(256) void k_chunk_scan(const int* __restrict__ cnt,
                                                    const int* __restrict__ bscan,
                                                    int* __restrict__ off_work)
{
    __shared__ int s[CHUNK];
    const int b = blockIdx.x, t = threadIdx.x;
    const int i = b * CHUNK + t;
    const int v = (i < N_NODES) ? cnt[i] : 0;
    s[t] = v; __syncthreads();
    for (int off = 1; off < CHUNK; off <<= 1) {
        const int x = (t >= off) ? s[t - off] : 0;
        __syncthreads();
        s[t] += x;
        __syncthreads();
    }
    if (i < N_NODES) off_work[i] = bscan[b] + s[t] - v;   // exclusive
}

__global__ void k_scatter(const int* __restrict__ ei, int* __restrict__ off_work,
                          int* __restrict__ srcS, int* __restrict__ dstS,
                          int* __restrict__ perm)
{
    const int e = blockIdx.x * 256 + threadIdx.x;
    if (e < N_EDGES) {
        const int d = ei[N_EDGES + e];
        const int pos = atomicAdd(&off_work[d], 1);
        srcS[pos] = ei[e];
        dstS[pos] = d;
        perm[pos] = e;
    }
}

// ---------------- prep: edge_attr (sorted order) -> padded bf16 [N_EDGES][16] ----------------
__global__ __launch_bounds__(256) void k_prep_ea(const float* __restrict__ ea,
                                                 const int* __restrict__ perm,
                                                 ushortT* __restrict__ ea16)
{
    const size_t i = (size_t)blockIdx.x * 256 + threadIdx.x;
    if (i >= (size_t)N_EDGES * 16) return;
    const int e = (int)(i >> 4), c = (int)(i & 15);
    const int pe = perm[e];
    ea16[i] = (c < EDGE_DIM) ? f2bf(ea[(size_t)pe * EDGE_DIM + c]) : (ushortT)0;
}

// ---------------- prep: W_msg -> B-fragment layout, K padded 139->160 (k>=139 -> 0) ----------------
__global__ __launch_bounds__(256) void k_prep_wmsg(const float* __restrict__ W,
                                                   ushortT* __restrict__ Wf)
{
    const int i = blockIdx.x * 256 + threadIdx.x;
    if (i >= DEPTH * 20480) return;
    const int d = i / 20480, r = i % 20480;
    const int j = r & 7, lane = (r >> 3) & 63, tile = r >> 9;
    const int ct = tile & 7, kt = tile >> 3;
    const int k = kt * 32 + ((lane >> 4) << 3) + j;
    const int c = ct * 16 + (lane & 15);
    Wf[i] = (k < HIDDEN + EDGE_DIM)
          ? f2bf(W[((size_t)d * (HIDDEN + EDGE_DIM) + k) * HIDDEN + c]) : (ushortT)0;
}

// ---------------- prep: W_up -> B-fragment layout, K = 256 ----------------
__global__ __launch_bounds__(256) void k_prep_wup(const float* __restrict__ W,
                                                  ushortT* __restrict__ Wf)
{
    const int i = blockIdx.x * 256 + threadIdx.x;
    if (i >= DEPTH * 32768) return;
    const int d = i / 32768, r = i % 32768;
    const int j = r & 7, lane = (r >> 3) & 63, tile = r >> 9;
    const int ct = tile & 7, kt = tile >> 3;
    const int k = kt * 32 + ((lane >> 4) << 3) + j;
    const int c = ct * 16 + (lane & 15);
    Wf[i] = f2bf(W[((size_t)d * 2 * HIDDEN + k) * HIDDEN + c]);
}

// ---------------- input projection: h16 = bf16(lrelu(x @ W_in + b_in)) ----------------
__global__ __launch_bounds__(128) void k_input_proj(const float* __restrict__ x,
                                                    const float* __restrict__ W,
                                                    const float* __restrict__ b,
                                                    ushortT* __restrict__ h16)
{
    const int t  = threadIdx.x;
    const int n0 = blockIdx.x * 8;
    __shared__ float sW[IN_DIM * HIDDEN];
    __shared__ float sx[8][IN_DIM];
    for (int i = t; i < IN_DIM * HIDDEN; i += 128) sW[i] = W[i];
    for (int i = t; i < 8 * IN_DIM; i += 128) {
        int n = i / IN_DIM, k = i % IN_DIM;
        sx[n][k] = x[(size_t)(n0 + n) * IN_DIM + k];
    }
    __syncthreads();
    const float bt = b[t];
    for (int n = 0; n < 8; ++n) {
        float acc = bt;
        #pragma unroll
        for (int k = 0; k < IN_DIM; ++k) acc += sx[n][k] * sW[k * HIDDEN + t];
        h16[(size_t)(n0 + n) * HIDDEN + t] = f2bf(lrelu(acc));
    }
}

// ------- fused edge message MFMA GEMM + lrelu + segmented-reduce scatter -------
// Column-ownership: wave w owns ct = {2w, 2w+1}; B fragments in registers (loaded once).
__global__ __launch_bounds__(256) void k_edge_mfma(const ushortT* __restrict__ h16,
                                                   const int*     __restrict__ srcS,
                                                   const int*     __restrict__ dstS,
                                                   const ushortT* __restrict__ ea16,
                                                   const ushortT* __restrict__ Wf,
                                                   const float*   __restrict__ bmsg,
                                                   float*         __restrict__ aggr)
{
    const int t    = threadIdx.x;
    const int wave = t >> 6, lane = t & 63;
    const int e0   = blockIdx.x * 64;

    // sA (bf16 A-tile, 21504B) and sMsg (fp32 messages, 33792B) alias the same LDS
    __shared__ __align__(16) unsigned char smem[64 * 132 * 4];
    ushortT (*sA)[168]   = reinterpret_cast<ushortT (*)[168]>(smem);
    float   (*sMsg)[132] = reinterpret_cast<float (*)[132]>(smem);
    __shared__ int sSrc[64];
    __shared__ int sDst[64];

    // B fragments in registers: wave owns ct0, ct0+1 (10 loads, reused 4x)
    const int ct0 = wave * 2;
    short8v B[5][2];
    const short8v* wp = reinterpret_cast<const short8v*>(Wf);
    #pragma unroll
    for (int kt = 0; kt < 5; ++kt) {
        B[kt][0] = wp[(size_t)(kt * 8 + ct0) * 64 + lane];
        B[kt][1] = wp[(size_t)(kt * 8 + ct0 + 1) * 64 + lane];
    }

    if (t < 64) { sSrc[t] = srcS[e0 + t]; sDst[t] = dstS[e0 + t]; }
    __syncthreads();

    // stage h16 rows: 64 edges x 16 uint4 (cols 0..127)
    for (int i = t; i < 64 * 16; i += 256) {
        const int e = i >> 4, q = i & 15;
        const uint4 v = reinterpret_cast<const uint4*>(h16)[(size_t)sSrc[e] * 16 + q];
        *reinterpret_cast<uint4*>(&sA[e][q * 8]) = v;
    }
    // stage compact edge_attr: 64 edges x 2 uint4 (cols 128..143; 139..143 are zeros)
    for (int i = t; i < 64 * 2; i += 256) {
        const int e = i >> 1, q = i & 1;
        const uint4 v = reinterpret_cast<const uint4*>(ea16)[((size_t)(e0 + e)) * 2 + q];
        *reinterpret_cast<uint4*>(&sA[e][128 + q * 8]) = v;
    }
    // zero cols 144..159 (Wf is zero there, but LDS garbage could be NaN: 0*NaN=NaN)
    if (t < 128) {
        const int e = t >> 1, q = t & 1;
        const uint4 z = {0u, 0u, 0u, 0u};
        *reinterpret_cast<uint4*>(&sA[e][144 + q * 8]) = z;
    }
    __syncthreads();

    float4v acc[4][2];
    #pragma unroll
    for (int m = 0; m < 4; ++m) { acc[m][0] = (float4v)(0.f); acc[m][1] = (float4v)(0.f); }

    const int kOff = (lane >> 4) * 8;
    #pragma unroll
    for (int m = 0; m < 4; ++m) {
        const int row = m * 16 + (lane & 15);
        #pragma unroll
        for (int kt = 0; kt < 5; ++kt) {
            const short8v a = *reinterpret_cast<const short8v*>(&sA[row][kt * 32 + kOff]);
            acc[m][0] = __builtin_amdgcn_mfma_f32_16x16x32_bf16(a, B[kt][0], acc[m][0], 0, 0, 0);
            acc[m][1] = __builtin_amdgcn_mfma_f32_16x16x32_bf16(a, B[kt][1], acc[m][1], 0, 0, 0);
        }
    }
    __syncthreads();   // all waves done reading sA; safe to overwrite with sMsg

    // bias + lrelu -> LDS message tile (wave writes its own 32 columns)
    const int col = lane & 15;
    const int r0  = (lane >> 4) * 4;
    #pragma unroll
    for (int c = 0; c < 2; ++c) {
        const int ccol = (ct0 + c) * 16 + col;
        const float bt = bmsg[ccol];
        #pragma unroll
        for (int m = 0; m < 4; ++m) {
            #pragma unroll
            for (int j = 0; j < 4; ++j) {
                sMsg[m * 16 + r0 + j][ccol] = lrelu(acc[m][c][j] + bt);
            }
        }
    }
    __syncthreads();

    // column-parallel segmented reduction over each 32-edge half
    const int half = t >> 7;
    const int c    = t & 127;
    const int base = half * 32;
    float a = 0.f;
    int cur = sDst[base];
    bool atStart = true;              // current run may extend before this half
    for (int e = base; e < base + 32; ++e) {
        const int d = sDst[e];
        if (d != cur) {
            if (atStart) atomicAdd(&aggr[(size_t)cur * HIDDEN + c], a);
            else         aggr[(size_t)cur * HIDDEN + c] = a;   // interior run: complete sum
            atStart = false; cur = d; a = 0.f;
        }
        a += sMsg[e][c];
    }
    atomicAdd(&aggr[(size_t)cur * HIDDEN + c], a);   // final run may continue past half
}

// ------- update MFMA GEMM: relu(cat[aggr, h16] @ W_up + b_up) -------
// Column-ownership: wave owns 2 ct; Bh in registers (16 loads / 48 MFMAs);
// lo-correction reuses Bh[0..3]. Stats per wave (exclusive cols), no barrier.
__global__ __launch_bounds__(256) void k_update_mfma(float*         __restrict__ aggr,
                                                     const ushortT* __restrict__ h16,
                                                     const ushortT* __restrict__ Wf,
                                                     const float*   __restrict__ bup,
                                                     float*         __restrict__ p_sum,
                                                     float*         __restrict__ p_sumsq)
{
    const int t    = threadIdx.x;
    const int wave = t >> 6, lane = t & 63;
    const int n0   = blockIdx.x * UB;

    __shared__ __align__(16) ushortT sA[UB][264];   // hi(aggr) 0..127, h16 128..255
    __shared__ __align__(16) ushortT sLo[UB][136];  // lo(aggr)

    // B fragments in registers
    const int ct0 = wave * 2;
    short8v Bh[8][2];
    const short8v* wp = reinterpret_cast<const short8v*>(Wf);
    #pragma unroll
    for (int kt = 0; kt < 8; ++kt) {
        Bh[kt][0] = wp[(size_t)(kt * 8 + ct0) * 64 + lane];
        Bh[kt][1] = wp[(size_t)(kt * 8 + ct0 + 1) * 64 + lane];
    }

    // stage aggr fp32 -> hi/lo bf16 split (4 float4 per thread)
    for (int i = t; i < UB * 32; i += 256) {
        const int n = i >> 5, q = i & 31;
        const float4 v = reinterpret_cast<const float4*>(aggr)[(size_t)(n0 + n) * 32 + q];
        union { ushortT s[4]; uint2 u; } hi, lo;
        #pragma unroll
        for (int j = 0; j < 4; ++j) {
            const float f = (&v.x)[j];
            const ushortT hb = f2bf(f);
            hi.s[j] = hb;
            lo.s[j] = f2bf(f - bf2f(hb));
        }
        *reinterpret_cast<uint2*>(&sA[n][q * 4])  = hi.u;
        *reinterpret_cast<uint2*>(&sLo[n][q * 4]) = lo.u;
    }
    // stage h16 (cols 128..255)
    for (int i = t; i < UB * 16; i += 256) {
        const int n = i >> 4, q = i & 15;
        const uint4 v = reinterpret_cast<const uint4*>(h16)[(size_t)(n0 + n) * 16 + q];
        *reinterpret_cast<uint4*>(&sA[n][128 + q * 8]) = v;
    }
    __syncthreads();

    float4v acc[2][2];
    #pragma unroll
    for (int m = 0; m < 2; ++m) { acc[m][0] = (float4v)(0.f); acc[m][1] = (float4v)(0.f); }

    const int kOff = (lane >> 4) * 8;
    #pragma unroll
    for (int m = 0; m < 2; ++m) {
        const int row = m * 16 + (lane & 15);
        #pragma unroll
        for (int kt = 0; kt < 8; ++kt) {
            const short8v a = *reinterpret_cast<const short8v*>(&sA[row][kt * 32 + kOff]);
            acc[m][0] = __builtin_amdgcn_mfma_f32_16x16x32_bf16(a, Bh[kt][0], acc[m][0], 0, 0, 0);
            acc[m][1] = __builtin_amdgcn_mfma_f32_16x16x32_bf16(a, Bh[kt][1], acc[m][1], 0, 0, 0);
        }
        #pragma unroll
        for (int kt = 0; kt < 4; ++kt) {   // lo correction over aggr half; W rows identical
            const short8v a = *reinterpret_cast<const short8v*>(&sLo[row][kt * 32 + kOff]);
            acc[m][0] = __builtin_amdgcn_mfma_f32_16x16x32_bf16(a, Bh[kt][0], acc[m][0], 0, 0, 0);
            acc[m][1] = __builtin_amdgcn_mfma_f32_16x16x32_bf16(a, Bh[kt][1], acc[m][1], 0, 0, 0);
        }
    }

    // epilogue: bias + relu, write fp32 in-place; per-wave column stats (exclusive)
    const int col = lane & 15;
    const int r0  = (lane >> 4) * 4;
    #pragma unroll
    for (int c = 0; c < 2; ++c) {
        const int ccol = (ct0 + c) * 16 + col;
        const float bt = bup[ccol];
        float s = 0.f, q = 0.f;
        #pragma unroll
        for (int m = 0; m < 2; ++m) {
            #pragma unroll
            for (int j = 0; j < 4; ++j) {
                const float v = fmaxf(acc[m][c][j] + bt, 0.f);
                s += v; q += v * v;
                aggr[(size_t)(n0 + m * 16 + r0 + j) * HIDDEN + ccol] = v;
            }
        }
        s += __shfl_xor(s, 16); s += __shfl_xor(s, 32);
        q += __shfl_xor(q, 16); q += __shfl_xor(q, 32);
        if (lane < 16) {
            p_sum  [(size_t)ccol * NBLK + blockIdx.x] = s;
            p_sumsq[(size_t)ccol * NBLK + blockIdx.x] = q;
        }
    }
}

// ------- BN reduce: one block per feature -------
__global__ __launch_bounds__(256) void k_bn_reduce(const float* __restrict__ p_sum,
                                                   const float* __restrict__ p_sumsq,
                                                   const float* __restrict__ gamma,
                                                   const float* __restrict__ beta,
                                                   float* __restrict__ scale,
                                                   float* __restrict__ shift)
{
    const int c = blockIdx.x, t = threadIdx.x;
    float s = 0.f, q = 0.f;
    for (int i = t; i < NBLK; i += 256) {
        s += p_sum  [(size_t)c * NBLK + i];
        q += p_sumsq[(size_t)c * NBLK + i];
    }
    #pragma unroll
    for (int off = 32; off > 0; off >>= 1) {
        s += __shfl_down(s, off);
        q += __shfl_down(q, off);
    }
    __shared__ float ls[4], lq[4];
    const int w = t >> 6;
    if ((t & 63) == 0) { ls[w] = s; lq[w] = q; }
    __syncthreads();
    if (t == 0) {
        s = ls[0] + ls[1] + ls[2] + ls[3];
        q = lq[0] + lq[1] + lq[2] + lq[3];
        const float mu  = s * (1.f / N_NODES);
        const float var = q * (1.f / N_NODES) - mu * mu;
        const float sc  = gamma[c] * rsqrtf(var + BN_EPS);
        scale[c] = sc;
        shift[c] = beta[c] - mu * sc;
    }
}

// ------- BN normalize: buf fp32 -> h16 bf16, and zero buf for next layer's aggr -------
__global__ __launch_bounds__(256) void k_bn_norm(float* __restrict__ buf,
                                                 const float* __restrict__ scale,
                                                 const float* __restrict__ shift,
                                                 ushortT* __restrict__ h16)
{
    const size_t i = (size_t)blockIdx.x * 256 + threadIdx.x;
    if (i >= (size_t)N_NODES * HIDDEN / 4) return;
    const float4 v = reinterpret_cast<const float4*>(buf)[i];
    const int c0 = (int)((i * 4) & (HIDDEN - 1));
    union { ushortT s[4]; uint2 u; } p;
    p.s[0] = f2bf(v.x * scale[c0 + 0] + shift[c0 + 0]);
    p.s[1] = f2bf(v.y * scale[c0 + 1] + shift[c0 + 1]);
    p.s[2] = f2bf(v.z * scale[c0 + 2] + shift[c0 + 2]);
    p.s[3] = f2bf(v.w * scale[c0 + 3] + shift[c0 + 3]);
    reinterpret_cast<uint2*>(h16)[i] = p.u;
    const float4 z = {0.f, 0.f, 0.f, 0.f};
    reinterpret_cast<float4*>(buf)[i] = z;   // fused memset for next layer
}

// ------- mean pool over graphs -------
__global__ void k_pool_cnt(const int* __restrict__ batch, float* __restrict__ cnt)
{
    const int n = blockIdx.x * 256 + threadIdx.x;
    if (n < N_NODES) atomicAdd(&cnt[batch[n]], 1.0f);
}

__global__ __launch_bounds__(128) void k_pool_sum(const ushortT* __restrict__ h16,
                                                  const int* __restrict__ batch,
                                                  float* __restrict__ pool)
{
    const int t  = threadIdx.x;
    const int n0 = blockIdx.x * 16;
    __shared__ int sb[16];
    if (t < 16) sb[t] = batch[n0 + t];
    __syncthreads();
    int g = sb[0];
    float acc = 0.f;
    for (int j = 0; j < 16; ++j) {
        const float v = bf2f(h16[(size_t)(n0 + j) * HIDDEN + t]);
        if (sb[j] != g) {
            atomicAdd(&pool[(size_t)g * HIDDEN + t], acc);
            g = sb[j];
            acc = v;
        } else {
            acc += v;
        }
    }
    atomicAdd(&pool[(size_t)g * HIDDEN + t], acc);
}

__global__ void k_pool_div(const float* __restrict__ pool,
                           const float* __restrict__ cnt,
                           float* __restrict__ out)
{
    const int i = blockIdx.x * 256 + threadIdx.x;
    if (i < N_GRAPHS * HIDDEN) {
        const int g = i >> 7;
        out[i] = pool[i] / fmaxf(cnt[g], 1.0f);
    }
}

extern "C" void kernel_launch(void* const* d_in, const int* in_sizes, int n_in,
                              void* d_out, int out_size, void* d_ws, size_t ws_size,
                              hipStream_t stream)
{
    const float* x     = (const float*)d_in[0];
    const int*   ei    = (const int*)  d_in[1];
    const float* ea    = (const float*)d_in[2];
    const int*   batch = (const int*)  d_in[3];
    const float* W_in  = (const float*)d_in[4];
    const float* b_in  = (const float*)d_in[5];
    const float* W_msg = (const float*)d_in[6];
    const float* b_msg = (const float*)d_in[7];
    const float* W_up  = (const float*)d_in[8];
    const float* b_up  = (const float*)d_in[9];
    const float* gamma = (const float*)d_in[10];
    const float* beta  = (const float*)d_in[11];
    float* out = (float*)d_out;

    // ---- workspace layout ----
    float*   aggr  = (float*)d_ws;                                   // N*128 fp32
    ushortT* h16   = (ushortT*)(aggr + (size_t)N_NODES * HIDDEN);    // N*128 bf16
    ushortT* ea16  = h16 + (size_t)N_NODES * HIDDEN;                 // E*16 bf16
    ushortT* wmsgf = ea16 + (size_t)N_EDGES * 16;                    // 4*20480
    ushortT* wupf  = wmsgf + DEPTH * 20480;                          // 4*32768
    float*   bn_scale = (float*)(wupf + DEPTH * 32768);              // 128
    float*   bn_shift = bn_scale + HIDDEN;                           // 128
    float*   pool     = bn_shift + HIDDEN;                           // G*128
    float*   cnt      = pool + (size_t)N_GRAPHS * HIDDEN;            // G
    float*   p_sum    = cnt + N_GRAPHS;                              // 128*NBLK
    float*   p_sumsq  = p_sum + (size_t)HIDDEN * NBLK;               // 128*NBLK
    int*     ecnt     = (int*)(p_sumsq + (size_t)HIDDEN * NBLK);     // N
    int*     off_work = ecnt + N_NODES;                              // N
    int*     bsum     = off_work + N_NODES;                          // NCHUNK
    int*     bscan    = bsum + 1024;                                 // NCHUNK
    int*     srcS     = bscan + 1024;                                // E
    int*     dstS     = srcS + N_EDGES;                              // E
    int*     perm     = dstS + N_EDGES;                              // E

    // ---- edge sort by dst (once; edge_index constant across layers) ----
    hipMemsetAsync(ecnt, 0, N_NODES * sizeof(int), stream);
    k_hist<<<(N_EDGES + 255) / 256, 256, 0, stream>>>(ei, ecnt);
    k_chunk_sum<<<NCHUNK, 256, 0, stream>>>(ecnt, bsum);
    k_scan_bsums<<<1, 1024, 0, stream>>>(bsum, bscan);
    k_chunk_scan<<<NCHUNK, 256, 0, stream>>>(ecnt, bscan, off_work);
    k_scatter<<<(N_EDGES + 255) / 256, 256, 0, stream>>>(ei, off_work, srcS, dstS, perm);

    // ---- one-time prep ----
    k_prep_ea<<<(N_EDGES * 16 + 255) / 256, 256, 0, stream>>>(ea, perm, ea16);
    k_prep_wmsg<<<(DEPTH * 20480 + 255) / 256, 256, 0, stream>>>(W_msg, wmsgf);
    k_prep_wup<<<(DEPTH * 32768 + 255) / 256, 256, 0, stream>>>(W_up, wupf);
    k_input_proj<<<N_NODES / 8, 128, 0, stream>>>(x, W_in, b_in, h16);

    hipMemsetAsync(aggr, 0, (size_t)N_NODES * HIDDEN * sizeof(float), stream);
    for (int d = 0; d < DEPTH; ++d) {
        k_edge_mfma<<<N_EDGES / 64, 256, 0, stream>>>(
            h16, srcS, dstS, ea16, wmsgf + (size_t)d * 20480,
            b_msg + (size_t)d * HIDDEN, aggr);
        k_update_mfma<<<N_NODES / UB, 256, 0, stream>>>(
            aggr, h16, wupf + (size_t)d * 32768, b_up + (size_t)d * HIDDEN,
            p_sum, p_sumsq);
        k_bn_reduce<<<HIDDEN, 256, 0, stream>>>(p_sum, p_sumsq,
                                                gamma + (size_t)d * HIDDEN,
                                                beta + (size_t)d * HIDDEN,
                                                bn_scale, bn_shift);
        k_bn_norm<<<(N_NODES * HIDDEN / 4 + 255) / 256, 256, 0, stream>>>(
            aggr, bn_scale, bn_shift, h16);   // also zeroes aggr for next layer
    }

    hipMemsetAsync(pool, 0, ((size_t)N_GRAPHS * HIDDEN + N_GRAPHS) * sizeof(float), stream);
    k_pool_cnt<<<(N_NODES + 255) / 256, 256, 0, stream>>>(batch, cnt);
    k_pool_sum<<<N_NODES / 16, 128, 0, stream>>>(h16, batch, pool);
    k_pool_div<<<(N_GRAPHS * HIDDEN + 255) / 256, 256, 0, stream>>>(pool, cnt, out);
}

// Round 6
// 883.380 us; speedup vs baseline: 4.8944x; 1.0607x over previous
//
#include <hip/hip_runtime.h>

#define N_NODES  200000
#define N_EDGES  600000
#define N_GRAPHS 4000
#define IN_DIM   25
#define EDGE_DIM 11
#define HIDDEN   128
#define DEPTH    4
#define BN_EPS   1e-5f

#define UB   32                 // nodes per block in update kernel
#define NBLK (N_NODES / UB)     // partial-stat rows
#define NEBLK (N_EDGES / 64)    // edge blocks
#define CHUNK  256
#define NCHUNK ((N_NODES + CHUNK - 1) / CHUNK)   // 782

typedef unsigned short ushortT;
typedef __attribute__((ext_vector_type(8))) short short8v;
typedef __attribute__((ext_vector_type(4))) float float4v;

__device__ __forceinline__ float lrelu(float v) { return v > 0.f ? v : 0.1f * v; }

__device__ __forceinline__ ushortT f2bf(float f) {
    unsigned u = __builtin_bit_cast(unsigned, f);
    u = (u + 0x7fffu + ((u >> 16) & 1u)) >> 16;
    return (ushortT)u;
}
__device__ __forceinline__ float bf2f(ushortT h) {
    unsigned u = ((unsigned)h) << 16;
    return __builtin_bit_cast(float, u);
}

// ================= counting sort of edges by dst (once per call) =================
__global__ void k_hist(const int* __restrict__ ei, int* __restrict__ cnt)
{
    const int e = blockIdx.x * 256 + threadIdx.x;
    if (e < N_EDGES) atomicAdd(&cnt[ei[N_EDGES + e]], 1);
}

__global__ __launch_bounds__(256) void k_chunk_sum(const int* __restrict__ cnt,
                                                   int* __restrict__ bsum)
{
    const int t = threadIdx.x;
    const int i = blockIdx.x * CHUNK + t;
    int v = (i < N_NODES) ? cnt[i] : 0;
    #pragma unroll
    for (int off = 32; off > 0; off >>= 1) v += __shfl_down(v, off);
    __shared__ int ws[4];
    if ((t & 63) == 0) ws[t >> 6] = v;
    __syncthreads();
    if (t == 0) bsum[blockIdx.x] = ws[0] + ws[1] + ws[2] + ws[3];
}

__global__ __launch_bounds__(1024) void k_scan_bsums(const int* __restrict__ bsum,
                                                     int* __restrict__ bscan)
{
    __shared__ int s[1024];
    const int t = threadIdx.x;
    const int v = (t < NCHUNK) ? bsum[t] : 0;
    s[t] = v; __syncthreads();
    for (int off = 1; off < 1024; off <<= 1) {
        const int x = (t >= off) ? s[t - off] : 0;
        __syncthreads();
        s[t] += x;
        __syncthreads();
    }
    if (t < NCHUNK) bscan[t] = s[t] - v;   // exclusive
}

__global__ __launch_bounds__(256) void k_chunk_scan(const int* __restrict__ cnt,
                                                    const int* __restrict__ bscan,
                                                    int* __restrict__ off_work)
{
    __shared__ int s[CHUNK];
    const int b = blockIdx.x, t = threadIdx.x;
    const int i = b * CHUNK + t;
    const int v = (i < N_NODES) ? cnt[i] : 0;
    s[t] = v; __syncthreads();
    for (int off = 1; off < CHUNK; off <<= 1) {
        const int x = (t >= off) ? s[t - off] : 0;
        __syncthreads();
        s[t] += x;
        __syncthreads();
    }
    if (i < N_NODES) off_work[i] = bscan[b] + s[t] - v;   // exclusive
}

__global__ void k_scatter(const int* __restrict__ ei, int* __restrict__ off_work,
                          int* __restrict__ srcS, int* __restrict__ dstS,
                          int* __restrict__ perm)
{
    const int e = blockIdx.x * 256 + threadIdx.x;
    if (e < N_EDGES) {
        const int d = ei[N_EDGES + e];
        const int pos = atomicAdd(&off_work[d], 1);
        srcS[pos] = ei[e];
        dstS[pos] = d;
        perm[pos] = e;
    }
}

// ------- needs-zero set: block-boundary dsts + zero-degree nodes (once per call) -------
__global__ void k_flag_ends(const int* __restrict__ dstS, int* __restrict__ flag)
{
    const int i = blockIdx.x * 256 + threadIdx.x;
    if (i < NEBLK * 4) {
        const int b = i >> 2, p = i & 3;
        const int pos = (p == 0) ? 0 : (p == 1) ? 31 : (p == 2) ? 32 : 63;
        flag[dstS[b * 64 + pos]] = 1;
    }
}

__global__ void k_flag_zdeg(const int* __restrict__ ecnt, int* __restrict__ flag)
{
    const int n = blockIdx.x * 256 + threadIdx.x;
    if (n < N_NODES && ecnt[n] == 0) flag[n] = 1;
}

__global__ void k_compact(const int* __restrict__ flag, int* __restrict__ zlist,
                          int* __restrict__ zcount)
{
    const int n = blockIdx.x * 256 + threadIdx.x;
    if (n < N_NODES && flag[n]) zlist[atomicAdd(zcount, 1)] = n;
}

// ------- per-layer: zero only the rows that receive atomics -------
__global__ __launch_bounds__(256) void k_zero_rows(const int* __restrict__ zlist,
                                                   const int* __restrict__ zcount,
                                                   float* __restrict__ aggr)
{
    const int total = zcount[0] * 32;
    const float4 z = {0.f, 0.f, 0.f, 0.f};
    for (int i = blockIdx.x * 256 + threadIdx.x; i < total; i += gridDim.x * 256) {
        const int row = zlist[i >> 5], q = i & 31;
        reinterpret_cast<float4*>(aggr)[(size_t)row * 32 + q] = z;
    }
}

// ---------------- prep: edge_attr (sorted order) -> padded bf16 [N_EDGES][16] ----------------
__global__ __launch_bounds__(256) void k_prep_ea(const float* __restrict__ ea,
                                                 const int* __restrict__ perm,
                                                 ushortT* __restrict__ ea16)
{
    const size_t i = (size_t)blockIdx.x * 256 + threadIdx.x;
    if (i >= (size_t)N_EDGES * 16) return;
    const int e = (int)(i >> 4), c = (int)(i & 15);
    const int pe = perm[e];
    ea16[i] = (c < EDGE_DIM) ? f2bf(ea[(size_t)pe * EDGE_DIM + c]) : (ushortT)0;
}

// ------- per-layer weight fold: fragment layouts with BN affine folded in -------
// msg: rows k<128 scaled by scale[k]; bias' = b + shift @ W[0:128]
// up:  rows k>=128 scaled by scale[k-128]; bias' = b + shift @ W[128:256]
__global__ __launch_bounds__(256) void k_fold(const float* __restrict__ Wm,
                                              const float* __restrict__ bm,
                                              const float* __restrict__ Wu,
                                              const float* __restrict__ bu,
                                              const float* __restrict__ scale,
                                              const float* __restrict__ shift,
                                              ushortT* __restrict__ WmF,
                                              float*   __restrict__ bmF,
                                              ushortT* __restrict__ WuF,
                                              float*   __restrict__ buF)
{
    const int b = blockIdx.x, t = threadIdx.x;
    if (b < 80) {                          // W_msg fragment: 20480 elems, K padded 139->160
        const int i = b * 256 + t;
        const int j = i & 7, lane = (i >> 3) & 63, tile = i >> 9;
        const int ct = tile & 7, kt = tile >> 3;
        const int k = kt * 32 + ((lane >> 4) << 3) + j;
        const int c = ct * 16 + (lane & 15);
        float v = (k < HIDDEN + EDGE_DIM) ? Wm[k * HIDDEN + c] : 0.f;
        if (k < HIDDEN) v *= scale[k];
        WmF[i] = f2bf(v);
    } else if (b < 208) {                  // W_up fragment: 32768 elems, K = 256
        const int i = (b - 80) * 256 + t;
        const int j = i & 7, lane = (i >> 3) & 63, tile = i >> 9;
        const int ct = tile & 7, kt = tile >> 3;
        const int k = kt * 32 + ((lane >> 4) << 3) + j;
        const int c = ct * 16 + (lane & 15);
        float v = Wu[k * HIDDEN + c];
        if (k >= HIDDEN) v *= scale[k - HIDDEN];
        WuF[i] = f2bf(v);
    } else if (b == 208) {
        if (t < HIDDEN) {
            float acc = bm[t];
            for (int k = 0; k < HIDDEN; ++k) acc += shift[k] * Wm[k * HIDDEN + t];
            bmF[t] = acc;
        }
    } else {
        if (t < HIDDEN) {
            float acc = bu[t];
            for (int k = 0; k < HIDDEN; ++k) acc += shift[k] * Wu[(HIDDEN + k) * HIDDEN + t];
            buF[t] = acc;
        }
    }
}

__global__ void k_init_affine(float* __restrict__ scale, float* __restrict__ shift)
{
    const int t = threadIdx.x;
    scale[t] = 1.f;
    shift[t] = 0.f;
}

// ---------------- input projection: h16 = bf16(lrelu(x @ W_in + b_in)) ----------------
__global__ __launch_bounds__(128) void k_input_proj(const float* __restrict__ x,
                                                    const float* __restrict__ W,
                                                    const float* __restrict__ b,
                                                    ushortT* __restrict__ h16)
{
    const int t  = threadIdx.x;
    const int n0 = blockIdx.x * 8;
    __shared__ float sW[IN_DIM * HIDDEN];
    __shared__ float sx[8][IN_DIM];
    for (int i = t; i < IN_DIM * HIDDEN; i += 128) sW[i] = W[i];
    for (int i = t; i < 8 * IN_DIM; i += 128) {
        int n = i / IN_DIM, k = i % IN_DIM;
        sx[n][k] = x[(size_t)(n0 + n) * IN_DIM + k];
    }
    __syncthreads();
    const float bt = b[t];
    for (int n = 0; n < 8; ++n) {
        float acc = bt;
        #pragma unroll
        for (int k = 0; k < IN_DIM; ++k) acc += sx[n][k] * sW[k * HIDDEN + t];
        h16[(size_t)(n0 + n) * HIDDEN + t] = f2bf(lrelu(acc));
    }
}

// ------- fused edge message MFMA GEMM + lrelu + segmented-reduce scatter -------
// Column-ownership: wave w owns ct = {2w, 2w+1}; B fragments in registers (loaded once).
__global__ __launch_bounds__(256) void k_edge_mfma(const ushortT* __restrict__ h16,
                                                   const int*     __restrict__ srcS,
                                                   const int*     __restrict__ dstS,
                                                   const ushortT* __restrict__ ea16,
                                                   const ushortT* __restrict__ Wf,
                                                   const float*   __restrict__ bmsg,
                                                   float*         __restrict__ aggr)
{
    const int t    = threadIdx.x;
    const int wave = t >> 6, lane = t & 63;
    const int e0   = blockIdx.x * 64;

    // sA (bf16 A-tile, 21504B) and sMsg (fp32 messages, 33792B) alias the same LDS
    __shared__ __align__(16) unsigned char smem[64 * 132 * 4];
    ushortT (*sA)[168]   = reinterpret_cast<ushortT (*)[168]>(smem);
    float   (*sMsg)[132] = reinterpret_cast<float (*)[132]>(smem);
    __shared__ int sSrc[64];
    __shared__ int sDst[64];

    // B fragments in registers: wave owns ct0, ct0+1 (10 loads, reused 4x)
    const int ct0 = wave * 2;
    short8v B[5][2];
    const short8v* wp = reinterpret_cast<const short8v*>(Wf);
    #pragma unroll
    for (int kt = 0; kt < 5; ++kt) {
        B[kt][0] = wp[(size_t)(kt * 8 + ct0) * 64 + lane];
        B[kt][1] = wp[(size_t)(kt * 8 + ct0 + 1) * 64 + lane];
    }

    if (t < 64) { sSrc[t] = srcS[e0 + t]; sDst[t] = dstS[e0 + t]; }
    __syncthreads();

    // stage h16 rows: 64 edges x 16 uint4 (cols 0..127)
    for (int i = t; i < 64 * 16; i += 256) {
        const int e = i >> 4, q = i & 15;
        const uint4 v = reinterpret_cast<const uint4*>(h16)[(size_t)sSrc[e] * 16 + q];
        *reinterpret_cast<uint4*>(&sA[e][q * 8]) = v;
    }
    // stage compact edge_attr: 64 edges x 2 uint4 (cols 128..143; 139..143 are zeros)
    for (int i = t; i < 64 * 2; i += 256) {
        const int e = i >> 1, q = i & 1;
        const uint4 v = reinterpret_cast<const uint4*>(ea16)[((size_t)(e0 + e)) * 2 + q];
        *reinterpret_cast<uint4*>(&sA[e][128 + q * 8]) = v;
    }
    // zero cols 144..159 (Wf is zero there, but LDS garbage could be NaN: 0*NaN=NaN)
    if (t < 128) {
        const int e = t >> 1, q = t & 1;
        const uint4 z = {0u, 0u, 0u, 0u};
        *reinterpret_cast<uint4*>(&sA[e][144 + q * 8]) = z;
    }
    __syncthreads();

    float4v acc[4][2];
    #pragma unroll
    for (int m = 0; m < 4; ++m) { acc[m][0] = (float4v)(0.f); acc[m][1] = (float4v)(0.f); }

    const int kOff = (lane >> 4) * 8;
    #pragma unroll
    for (int m = 0; m < 4; ++m) {
        const int row = m * 16 + (lane & 15);
        #pragma unroll
        for (int kt = 0; kt < 5; ++kt) {
            const short8v a = *reinterpret_cast<const short8v*>(&sA[row][kt * 32 + kOff]);
            acc[m][0] = __builtin_amdgcn_mfma_f32_16x16x32_bf16(a, B[kt][0], acc[m][0], 0, 0, 0);
            acc[m][1] = __builtin_amdgcn_mfma_f32_16x16x32_bf16(a, B[kt][1], acc[m][1], 0, 0, 0);
        }
    }
    __syncthreads();   // all waves done reading sA; safe to overwrite with sMsg

    // bias + lrelu -> LDS message tile (wave writes its own 32 columns)
    const int col = lane & 15;
    const int r0  = (lane >> 4) * 4;
    #pragma unroll
    for (int c = 0; c < 2; ++c) {
        const int ccol = (ct0 + c) * 16 + col;
        const float bt = bmsg[ccol];
        #pragma unroll
        for (int m = 0; m < 4; ++m) {
            #pragma unroll
            for (int j = 0; j < 4; ++j) {
                sMsg[m * 16 + r0 + j][ccol] = lrelu(acc[m][c][j] + bt);
            }
        }
    }
    __syncthreads();

    // column-parallel segmented reduction over each 32-edge half.
    // Interior runs are complete sums -> plain store (aggr may be stale there, that's fine).
    // Boundary runs (first/last of each half) -> atomicAdd into pre-zeroed rows (k_zero_rows).
    const int half = t >> 7;
    const int c    = t & 127;
    const int base = half * 32;
    float a = 0.f;
    int cur = sDst[base];
    bool atStart = true;              // current run may extend before this half
    for (int e = base; e < base + 32; ++e) {
        const int d = sDst[e];
        if (d != cur) {
            if (atStart) atomicAdd(&aggr[(size_t)cur * HIDDEN + c], a);
            else         aggr[(size_t)cur * HIDDEN + c] = a;   // interior run: complete sum
            atStart = false; cur = d; a = 0.f;
        }
        a += sMsg[e][c];
    }
    atomicAdd(&aggr[(size_t)cur * HIDDEN + c], a);   // final run may continue past half
}

// ------- update MFMA GEMM: out = relu(cat[aggr, h16] @ W_up' + b_up') -------
// Writes bf16 raw `out` (BN affine applied by NEXT layer's folded weights).
// Column-ownership; Bh in registers; lo-correction reuses Bh[0..3]; stats per wave.
__global__ __launch_bounds__(256) void k_update_mfma(const float*   __restrict__ aggr,
                                                     const ushortT* __restrict__ h16,
                                                     const ushortT* __restrict__ Wf,
                                                     const float*   __restrict__ bup,
                                                     ushortT*       __restrict__ hout,
                                                     float*         __restrict__ p_sum,
                                                     float*         __restrict__ p_sumsq)
{
    const int t    = threadIdx.x;
    const int wave = t >> 6, lane = t & 63;
    const int n0   = blockIdx.x * UB;

    __shared__ __align__(16) ushortT sA[UB][264];   // hi(aggr) 0..127, h16 128..255
    __shared__ __align__(16) ushortT sLo[UB][136];  // lo(aggr)

    // B fragments in registers
    const int ct0 = wave * 2;
    short8v Bh[8][2];
    const short8v* wp = reinterpret_cast<const short8v*>(Wf);
    #pragma unroll
    for (int kt = 0; kt < 8; ++kt) {
        Bh[kt][0] = wp[(size_t)(kt * 8 + ct0) * 64 + lane];
        Bh[kt][1] = wp[(size_t)(kt * 8 + ct0 + 1) * 64 + lane];
    }

    // stage aggr fp32 -> hi/lo bf16 split
    for (int i = t; i < UB * 32; i += 256) {
        const int n = i >> 5, q = i & 31;
        const float4 v = reinterpret_cast<const float4*>(aggr)[(size_t)(n0 + n) * 32 + q];
        union { ushortT s[4]; uint2 u; } hi, lo;
        #pragma unroll
        for (int j = 0; j < 4; ++j) {
            const float f = (&v.x)[j];
            const ushortT hb = f2bf(f);
            hi.s[j] = hb;
            lo.s[j] = f2bf(f - bf2f(hb));
        }
        *reinterpret_cast<uint2*>(&sA[n][q * 4])  = hi.u;
        *reinterpret_cast<uint2*>(&sLo[n][q * 4]) = lo.u;
    }
    // stage h16 (cols 128..255)
    for (int i = t; i < UB * 16; i += 256) {
        const int n = i >> 4, q = i & 15;
        const uint4 v = reinterpret_cast<const uint4*>(h16)[(size_t)(n0 + n) * 16 + q];
        *reinterpret_cast<uint4*>(&sA[n][128 + q * 8]) = v;
    }
    __syncthreads();

    float4v acc[2][2];
    #pragma unroll
    for (int m = 0; m < 2; ++m) { acc[m][0] = (float4v)(0.f); acc[m][1] = (float4v)(0.f); }

    const int kOff = (lane >> 4) * 8;
    #pragma unroll
    for (int m = 0; m < 2; ++m) {
        const int row = m * 16 + (lane & 15);
        #pragma unroll
        for (int kt = 0; kt < 8; ++kt) {
            const short8v a = *reinterpret_cast<const short8v*>(&sA[row][kt * 32 + kOff]);
            acc[m][0] = __builtin_amdgcn_mfma_f32_16x16x32_bf16(a, Bh[kt][0], acc[m][0], 0, 0, 0);
            acc[m][1] = __builtin_amdgcn_mfma_f32_16x16x32_bf16(a, Bh[kt][1], acc[m][1], 0, 0, 0);
        }
        #pragma unroll
        for (int kt = 0; kt < 4; ++kt) {   // lo correction over aggr half; W rows identical
            const short8v a = *reinterpret_cast<const short8v*>(&sLo[row][kt * 32 + kOff]);
            acc[m][0] = __builtin_amdgcn_mfma_f32_16x16x32_bf16(a, Bh[kt][0], acc[m][0], 0, 0, 0);
            acc[m][1] = __builtin_amdgcn_mfma_f32_16x16x32_bf16(a, Bh[kt][1], acc[m][1], 0, 0, 0);
        }
    }

    // epilogue: bias + relu, write bf16 raw out; per-wave column stats (exclusive cols)
    const int col = lane & 15;
    const int r0  = (lane >> 4) * 4;
    #pragma unroll
    for (int c = 0; c < 2; ++c) {
        const int ccol = (ct0 + c) * 16 + col;
        const float bt = bup[ccol];
        float s = 0.f, q = 0.f;
        #pragma unroll
        for (int m = 0; m < 2; ++m) {
            #pragma unroll
            for (int j = 0; j < 4; ++j) {
                const float v = fmaxf(acc[m][c][j] + bt, 0.f);
                s += v; q += v * v;
                hout[(size_t)(n0 + m * 16 + r0 + j) * HIDDEN + ccol] = f2bf(v);
            }
        }
        s += __shfl_xor(s, 16); s += __shfl_xor(s, 32);
        q += __shfl_xor(q, 16); q += __shfl_xor(q, 32);
        if (lane < 16) {
            p_sum  [(size_t)ccol * NBLK + blockIdx.x] = s;
            p_sumsq[(size_t)ccol * NBLK + blockIdx.x] = q;
        }
    }
}

// ------- BN reduce: one block per feature -> scale/shift for the NEXT consumer -------
__global__ __launch_bounds__(256) void k_bn_reduce(const float* __restrict__ p_sum,
                                                   const float* __restrict__ p_sumsq,
                                                   const float* __restrict__ gamma,
                                                   const float* __restrict__ beta,
                                                   float* __restrict__ scale,
                                                   float* __restrict__ shift)
{
    const int c = blockIdx.x, t = threadIdx.x;
    float s = 0.f, q = 0.f;
    for (int i = t; i < NBLK; i += 256) {
        s += p_sum  [(size_t)c * NBLK + i];
        q += p_sumsq[(size_t)c * NBLK + i];
    }
    #pragma unroll
    for (int off = 32; off > 0; off >>= 1) {
        s += __shfl_down(s, off);
        q += __shfl_down(q, off);
    }
    __shared__ float ls[4], lq[4];
    const int w = t >> 6;
    if ((t & 63) == 0) { ls[w] = s; lq[w] = q; }
    __syncthreads();
    if (t == 0) {
        s = ls[0] + ls[1] + ls[2] + ls[3];
        q = lq[0] + lq[1] + lq[2] + lq[3];
        const float mu  = s * (1.f / N_NODES);
        const float var = q * (1.f / N_NODES) - mu * mu;
        const float sc  = gamma[c] * rsqrtf(var + BN_EPS);
        scale[c] = sc;
        shift[c] = beta[c] - mu * sc;
    }
}

// ------- mean pool over graphs (applies final BN affine inline) -------
__global__ void k_pool_cnt(const int* __restrict__ batch, float* __restrict__ cnt)
{
    const int n = blockIdx.x * 256 + threadIdx.x;
    if (n < N_NODES) atomicAdd(&cnt[batch[n]], 1.0f);
}

__global__ __launch_bounds__(128) void k_pool_sum(const ushortT* __restrict__ h16,
                                                  const int* __restrict__ batch,
                                                  const float* __restrict__ scale,
                                                  const float* __restrict__ shift,
                                                  float* __restrict__ pool)
{
    const int t  = threadIdx.x;
    const int n0 = blockIdx.x * 16;
    __shared__ int sb[16];
    if (t < 16) sb[t] = batch[n0 + t];
    __syncthreads();
    const float sc = scale[t], sh = shift[t];
    int g = sb[0];
    float acc = 0.f;
    for (int j = 0; j < 16; ++j) {
        const float v = sc * bf2f(h16[(size_t)(n0 + j) * HIDDEN + t]) + sh;
        if (sb[j] != g) {
            atomicAdd(&pool[(size_t)g * HIDDEN + t], acc);
            g = sb[j];
            acc = v;
        } else {
            acc += v;
        }
    }
    atomicAdd(&pool[(size_t)g * HIDDEN + t], acc);
}

__global__ void k_pool_div(const float* __restrict__ pool,
                           const float* __restrict__ cnt,
                           float* __restrict__ out)
{
    const int i = blockIdx.x * 256 + threadIdx.x;
    if (i < N_GRAPHS * HIDDEN) {
        const int g = i >> 7;
        out[i] = pool[i] / fmaxf(cnt[g], 1.0f);
    }
}

extern "C" void kernel_launch(void* const* d_in, const int* in_sizes, int n_in,
                              void* d_out, int out_size, void* d_ws, size_t ws_size,
                              hipStream_t stream)
{
    const float* x     = (const float*)d_in[0];
    const int*   ei    = (const int*)  d_in[1];
    const float* ea    = (const float*)d_in[2];
    const int*   batch = (const int*)  d_in[3];
    const float* W_in  = (const float*)d_in[4];
    const float* b_in  = (const float*)d_in[5];
    const float* W_msg = (const float*)d_in[6];
    const float* b_msg = (const float*)d_in[7];
    const float* W_up  = (const float*)d_in[8];
    const float* b_up  = (const float*)d_in[9];
    const float* gamma = (const float*)d_in[10];
    const float* beta  = (const float*)d_in[11];
    float* out = (float*)d_out;

    // ---- workspace layout ----
    float*   aggr  = (float*)d_ws;                                   // N*128 fp32
    ushortT* hA    = (ushortT*)(aggr + (size_t)N_NODES * HIDDEN);    // N*128 bf16
    ushortT* hB    = hA + (size_t)N_NODES * HIDDEN;                  // N*128 bf16
    ushortT* ea16  = hB + (size_t)N_NODES * HIDDEN;                  // E*16 bf16
    ushortT* wmsgfA = ea16 + (size_t)N_EDGES * 16;                   // 20480
    ushortT* wupfA  = wmsgfA + 20480;                                // 32768
    float*   biasM  = (float*)(wupfA + 32768);                       // 128
    float*   biasU  = biasM + HIDDEN;                                // 128
    float*   bn_scale = biasU + HIDDEN;                              // 128
    float*   bn_shift = bn_scale + HIDDEN;                           // 128
    float*   pool     = bn_shift + HIDDEN;                           // G*128
    float*   cnt      = pool + (size_t)N_GRAPHS * HIDDEN;            // G
    float*   p_sum    = cnt + N_GRAPHS;                              // 128*NBLK
    float*   p_sumsq  = p_sum + (size_t)HIDDEN * NBLK;               // 128*NBLK
    int*     ecnt     = (int*)(p_sumsq + (size_t)HIDDEN * NBLK);     // N
    int*     off_work = ecnt + N_NODES;                              // N
    int*     bsum     = off_work + N_NODES;                          // 1024
    int*     bscan    = bsum + 1024;                                 // 1024
    int*     srcS     = bscan + 1024;                                // E
    int*     dstS     = srcS + N_EDGES;                              // E
    int*     perm     = dstS + N_EDGES;                              // E
    int*     flag     = perm + N_EDGES;                              // N
    int*     zlist    = flag + N_NODES;                              // N
    int*     zcount   = zlist + N_NODES;                             // 1

    // ---- edge sort by dst + needs-zero set (once; edge_index constant) ----
    hipMemsetAsync(ecnt, 0, N_NODES * sizeof(int), stream);
    hipMemsetAsync(flag, 0, N_NODES * sizeof(int), stream);
    hipMemsetAsync(zcount, 0, sizeof(int), stream);
    k_hist<<<(N_EDGES + 255) / 256, 256, 0, stream>>>(ei, ecnt);
    k_chunk_sum<<<NCHUNK, 256, 0, stream>>>(ecnt, bsum);
    k_scan_bsums<<<1, 1024, 0, stream>>>(bsum, bscan);
    k_chunk_scan<<<NCHUNK, 256, 0, stream>>>(ecnt, bscan, off_work);
    k_scatter<<<(N_EDGES + 255) / 256, 256, 0, stream>>>(ei, off_work, srcS, dstS, perm);
    k_flag_ends<<<(NEBLK * 4 + 255) / 256, 256, 0, stream>>>(dstS, flag);
    k_flag_zdeg<<<(N_NODES + 255) / 256, 256, 0, stream>>>(ecnt, flag);
    k_compact<<<(N_NODES + 255) / 256, 256, 0, stream>>>(flag, zlist, zcount);

    // ---- one-time prep ----
    k_prep_ea<<<(N_EDGES * 16 + 255) / 256, 256, 0, stream>>>(ea, perm, ea16);
    k_input_proj<<<N_NODES / 8, 128, 0, stream>>>(x, W_in, b_in, hA);
    k_init_affine<<<1, 128, 0, stream>>>(bn_scale, bn_shift);

    ushortT* hcur = hA;
    ushortT* hnext = hB;
    for (int d = 0; d < DEPTH; ++d) {
        k_fold<<<210, 256, 0, stream>>>(
            W_msg + (size_t)d * (HIDDEN + EDGE_DIM) * HIDDEN, b_msg + (size_t)d * HIDDEN,
            W_up + (size_t)d * 2 * HIDDEN * HIDDEN, b_up + (size_t)d * HIDDEN,
            bn_scale, bn_shift, wmsgfA, biasM, wupfA, biasU);
        k_zero_rows<<<1024, 256, 0, stream>>>(zlist, zcount, aggr);
        k_edge_mfma<<<N_EDGES / 64, 256, 0, stream>>>(
            hcur, srcS, dstS, ea16, wmsgfA, biasM, aggr);
        k_update_mfma<<<N_NODES / UB, 256, 0, stream>>>(
            aggr, hcur, wupfA, biasU, hnext, p_sum, p_sumsq);
        k_bn_reduce<<<HIDDEN, 256, 0, stream>>>(p_sum, p_sumsq,
                                                gamma + (size_t)d * HIDDEN,
                                                beta + (size_t)d * HIDDEN,
                                                bn_scale, bn_shift);
        ushortT* tmp = hcur; hcur = hnext; hnext = tmp;
    }

    hipMemsetAsync(pool, 0, ((size_t)N_GRAPHS * HIDDEN + N_GRAPHS) * sizeof(float), stream);
    k_pool_cnt<<<(N_NODES + 255) / 256, 256, 0, stream>>>(batch, cnt);
    k_pool_sum<<<N_NODES / 16, 128, 0, stream>>>(hcur, batch, bn_scale, bn_shift, pool);
    k_pool_div<<<(N_GRAPHS * HIDDEN + 255) / 256, 256, 0, stream>>>(pool, cnt, out);
}